// Round 1
// baseline (956.010 us; speedup 1.0000x reference)
//
#include <hip/hip_runtime.h>
#include <math.h>

// ---------------------------------------------------------------------------
// TopoGAT: 2-layer GAT on MI355X.
// Pipeline: deg-histogram -> exclusive scan -> CSR fill (by dst) ->
//   xform1 (h1 = [x|topo]@W1, alpha_src/dst per head) ->
//   agg1   (per-dst softmax-weighted gather, ELU) ->
//   xform2 (g = h2@W2, alpha scalars) ->
//   agg2   (gather + log_softmax) -> d_out.
// Softmax max-subtraction skipped: logits bounded (weights scaled 0.1),
// exp(e) safe in fp32 and mathematically identical after normalization.
// ---------------------------------------------------------------------------

__global__ void k_zero_i32(int* __restrict__ p, int n) {
    int i = blockIdx.x * blockDim.x + threadIdx.x;
    if (i < n) p[i] = 0;
}

__global__ void k_hist(const int* __restrict__ dst, int* __restrict__ deg, int E) {
    int e = blockIdx.x * blockDim.x + threadIdx.x;
    if (e < E) atomicAdd(&deg[dst[e]], 1);
}

// Block scans 1024 elements (256 threads x 4). Writes per-element exclusive
// prefix (block-local) to rowptr and block total to partials[blk].
__global__ __launch_bounds__(256) void k_scan1(const int* __restrict__ deg,
                                               int* __restrict__ rowptr,
                                               int* __restrict__ partials, int N) {
    __shared__ int wsum[4];
    int tid = threadIdx.x, lane = tid & 63, wv = tid >> 6;
    int base = blockIdx.x * 1024 + tid * 4;
    int d0 = (base + 0 < N) ? deg[base + 0] : 0;
    int d1 = (base + 1 < N) ? deg[base + 1] : 0;
    int d2 = (base + 2 < N) ? deg[base + 2] : 0;
    int d3 = (base + 3 < N) ? deg[base + 3] : 0;
    int tsum = d0 + d1 + d2 + d3;
    int v = tsum;
    #pragma unroll
    for (int ofs = 1; ofs < 64; ofs <<= 1) {
        int t = __shfl_up(v, ofs);
        if (lane >= ofs) v += t;
    }
    if (lane == 63) wsum[wv] = v;
    __syncthreads();
    int woff = 0;
    for (int i = 0; i < wv; i++) woff += wsum[i];
    int ex = woff + v - tsum;  // exclusive prefix for this thread
    if (base + 0 < N) rowptr[base + 0] = ex;
    if (base + 1 < N) rowptr[base + 1] = ex + d0;
    if (base + 2 < N) rowptr[base + 2] = ex + d0 + d1;
    if (base + 3 < N) rowptr[base + 3] = ex + d0 + d1 + d2;
    if (tid == 255) partials[blockIdx.x] = woff + v;  // block total
}

// Single block exclusive-scans partials (NB <= 128).
__global__ __launch_bounds__(128) void k_scan2(int* __restrict__ partials, int NB) {
    __shared__ int wsum[2];
    int tid = threadIdx.x, lane = tid & 63, wv = tid >> 6;
    int p = (tid < NB) ? partials[tid] : 0;
    int v = p;
    #pragma unroll
    for (int ofs = 1; ofs < 64; ofs <<= 1) {
        int t = __shfl_up(v, ofs);
        if (lane >= ofs) v += t;
    }
    if (lane == 63) wsum[wv] = v;
    __syncthreads();
    int wo = (wv == 1) ? wsum[0] : 0;
    if (tid < NB) partials[tid] = wo + v - p;
}

__global__ void k_scan3(int* __restrict__ rowptr, int* __restrict__ cursor,
                        const int* __restrict__ partials, int N, int E) {
    int i = blockIdx.x * blockDim.x + threadIdx.x;
    if (i < N) {
        int r = rowptr[i] + partials[i >> 10];
        rowptr[i] = r;
        cursor[i] = r;
    }
    if (i == N) rowptr[N] = E;
}

__global__ void k_fill(const int* __restrict__ src, const int* __restrict__ dst,
                       int* __restrict__ cursor, int* __restrict__ csr, int E) {
    int e = blockIdx.x * blockDim.x + threadIdx.x;
    if (e < E) {
        int p = atomicAdd(&cursor[dst[e]], 1);
        csr[p] = src[e];
    }
}

// h1[n][64] = [x[n]|topo[n]] @ W1 ; as1[n][8], ad1[n][8] head-wise attention dots.
// One wave per node; lane = output column (head = lane>>3, chan = lane&7).
__global__ __launch_bounds__(256) void k_xform1(const float* __restrict__ x,
                                                const float* __restrict__ topo,
                                                const float* __restrict__ W1,
                                                const float* __restrict__ asrc,
                                                const float* __restrict__ adst,
                                                float* __restrict__ h1,
                                                float* __restrict__ as1,
                                                float* __restrict__ ad1, int N) {
    __shared__ float Wl[136 * 64];
    __shared__ float asl[64], adl[64];
    int tid = threadIdx.x;
    for (int i = tid; i < 136 * 64; i += 256) Wl[i] = W1[i];
    if (tid < 64) { asl[tid] = asrc[tid]; adl[tid] = adst[tid]; }
    __syncthreads();
    int lane = tid & 63;
    int n = blockIdx.x * 4 + (tid >> 6);
    if (n >= N) return;
    float xr0 = x[n * 128 + lane];
    float xr1 = x[n * 128 + 64 + lane];
    float xt = (lane < 8) ? topo[n * 8 + lane] : 0.0f;
    float acc = 0.f;
    #pragma unroll
    for (int k = 0; k < 64; k++) acc = fmaf(__shfl(xr0, k), Wl[k * 64 + lane], acc);
    #pragma unroll
    for (int k = 0; k < 64; k++) acc = fmaf(__shfl(xr1, k), Wl[(64 + k) * 64 + lane], acc);
    #pragma unroll
    for (int k = 0; k < 8; k++)  acc = fmaf(__shfl(xt, k), Wl[(128 + k) * 64 + lane], acc);
    h1[n * 64 + lane] = acc;
    float sv = acc * asl[lane];
    float dv = acc * adl[lane];
    sv += __shfl_xor(sv, 1); sv += __shfl_xor(sv, 2); sv += __shfl_xor(sv, 4);
    dv += __shfl_xor(dv, 1); dv += __shfl_xor(dv, 2); dv += __shfl_xor(dv, 4);
    if ((lane & 7) == 0) {
        as1[n * 8 + (lane >> 3)] = sv;
        ad1[n * 8 + (lane >> 3)] = dv;
    }
}

// Per-dst softmax-weighted aggregation over in-edges (+ implicit self loop).
__global__ __launch_bounds__(256) void k_agg1(const float* __restrict__ h1,
                                              const float* __restrict__ as1,
                                              const float* __restrict__ ad1,
                                              const float* __restrict__ b1,
                                              const int* __restrict__ rowptr,
                                              const int* __restrict__ csr,
                                              float* __restrict__ h2, int N) {
    int tid = threadIdx.x, lane = tid & 63;
    int n = blockIdx.x * 4 + (tid >> 6);
    if (n >= N) return;
    int myh = lane >> 3;
    float ad_d = ad1[n * 8 + myh];
    // self loop (src == dst == n)
    float e0 = as1[n * 8 + myh] + ad_d;
    float w = __expf(e0 >= 0.f ? e0 : 0.2f * e0);
    float acc = w * h1[n * 64 + lane];
    float z = w;
    int j0 = rowptr[n], j1 = rowptr[n + 1];
    for (int j = j0; j < j1; ++j) {
        int s = csr[j];
        float e = as1[s * 8 + myh] + ad_d;
        float ww = __expf(e >= 0.f ? e : 0.2f * e);
        acc = fmaf(ww, h1[s * 64 + lane], acc);
        z += ww;
    }
    float v = acc / (z + 1e-16f) + b1[lane];
    h2[n * 64 + lane] = v > 0.f ? v : (__expf(v) - 1.f);  // ELU
}

// g[n][40] = h2[n] @ W2 ; scalar attention dots as2[n], ad2[n].
__global__ __launch_bounds__(256) void k_xform2(const float* __restrict__ h2,
                                                const float* __restrict__ W2,
                                                const float* __restrict__ asrc2,
                                                const float* __restrict__ adst2,
                                                float* __restrict__ g,
                                                float* __restrict__ as2,
                                                float* __restrict__ ad2, int N) {
    __shared__ float Wl[64 * 40];
    __shared__ float asl[40], adl[40];
    int tid = threadIdx.x;
    for (int i = tid; i < 64 * 40; i += 256) Wl[i] = W2[i];
    if (tid < 40) { asl[tid] = asrc2[tid]; adl[tid] = adst2[tid]; }
    __syncthreads();
    int lane = tid & 63;
    int n = blockIdx.x * 4 + (tid >> 6);
    if (n >= N) return;
    int c = (lane < 40) ? lane : 0;  // clamp so idle lanes stay in-bounds
    float hr = h2[n * 64 + lane];
    float acc = 0.f;
    #pragma unroll
    for (int k = 0; k < 64; k++) acc = fmaf(__shfl(hr, k), Wl[k * 40 + c], acc);
    float sv = (lane < 40) ? acc * asl[c] : 0.f;
    float dv = (lane < 40) ? acc * adl[c] : 0.f;
    #pragma unroll
    for (int ofs = 1; ofs < 64; ofs <<= 1) {
        sv += __shfl_xor(sv, ofs);
        dv += __shfl_xor(dv, ofs);
    }
    if (lane == 0) { as2[n] = sv; ad2[n] = dv; }
    if (lane < 40) g[n * 40 + lane] = acc;
}

// Layer-2 aggregation + bias + log_softmax.
__global__ __launch_bounds__(256) void k_agg2(const float* __restrict__ g,
                                              const float* __restrict__ as2,
                                              const float* __restrict__ ad2,
                                              const float* __restrict__ b2,
                                              const int* __restrict__ rowptr,
                                              const int* __restrict__ csr,
                                              float* __restrict__ out, int N) {
    int tid = threadIdx.x, lane = tid & 63;
    int n = blockIdx.x * 4 + (tid >> 6);
    if (n >= N) return;
    int c = (lane < 40) ? lane : 0;
    float add = ad2[n];
    float e0 = as2[n] + add;
    float w = __expf(e0 >= 0.f ? e0 : 0.2f * e0);
    float acc = w * g[n * 40 + c];
    float z = w;
    int j0 = rowptr[n], j1 = rowptr[n + 1];
    for (int j = j0; j < j1; ++j) {
        int s = csr[j];
        float e = as2[s] + add;
        float ww = __expf(e >= 0.f ? e : 0.2f * e);
        acc = fmaf(ww, g[s * 40 + c], acc);
        z += ww;
    }
    float logit = acc / (z + 1e-16f) + b2[c];
    float mv = (lane < 40) ? logit : -INFINITY;
    #pragma unroll
    for (int ofs = 1; ofs < 64; ofs <<= 1) mv = fmaxf(mv, __shfl_xor(mv, ofs));
    float ev = (lane < 40) ? __expf(logit - mv) : 0.f;
    #pragma unroll
    for (int ofs = 1; ofs < 64; ofs <<= 1) ev += __shfl_xor(ev, ofs);
    if (lane < 40) out[n * 40 + lane] = logit - mv - __logf(ev);
}

extern "C" void kernel_launch(void* const* d_in, const int* in_sizes, int n_in,
                              void* d_out, int out_size, void* d_ws, size_t ws_size,
                              hipStream_t stream) {
    const float* x    = (const float*)d_in[0];
    const float* topo = (const float*)d_in[1];
    const int*   ei   = (const int*)d_in[2];
    const float* W1   = (const float*)d_in[3];
    const float* a_s1 = (const float*)d_in[4];
    const float* a_d1 = (const float*)d_in[5];
    const float* b1   = (const float*)d_in[6];
    const float* W2   = (const float*)d_in[7];
    const float* a_s2 = (const float*)d_in[8];
    const float* a_d2 = (const float*)d_in[9];
    const float* b2   = (const float*)d_in[10];
    float* out = (float*)d_out;

    int N = in_sizes[0] / 128;
    int E = in_sizes[2] / 2;
    const int* esrc = ei;
    const int* edst = ei + E;

    char* ws = (char*)d_ws;
    size_t off = 0;
    auto alloc = [&](size_t bytes) -> void* {
        void* p = ws + off;
        off = (off + bytes + 255) & ~(size_t)255;
        return p;
    };
    float* h1     = (float*)alloc((size_t)N * 64 * 4);
    float* as1    = (float*)alloc((size_t)N * 8 * 4);
    float* ad1    = (float*)alloc((size_t)N * 8 * 4);
    float* h2     = (float*)alloc((size_t)N * 64 * 4);
    float* gbuf   = (float*)alloc((size_t)N * 40 * 4);
    float* as2    = (float*)alloc((size_t)N * 4);
    float* ad2    = (float*)alloc((size_t)N * 4);
    int*   deg    = (int*)alloc((size_t)N * 4);
    int*   rowptr = (int*)alloc((size_t)(N + 1) * 4);
    int*   cursor = (int*)alloc((size_t)N * 4);
    int*   csr    = (int*)alloc((size_t)E * 4);
    int NB = (N + 1023) / 1024;
    int*   partials = (int*)alloc((size_t)NB * 4);

    k_zero_i32<<<(N + 255) / 256, 256, 0, stream>>>(deg, N);
    k_hist<<<(E + 255) / 256, 256, 0, stream>>>(edst, deg, E);
    k_scan1<<<NB, 256, 0, stream>>>(deg, rowptr, partials, N);
    k_scan2<<<1, 128, 0, stream>>>(partials, NB);
    k_scan3<<<(N + 1 + 255) / 256, 256, 0, stream>>>(rowptr, cursor, partials, N, E);
    k_fill<<<(E + 255) / 256, 256, 0, stream>>>(esrc, edst, cursor, csr, E);

    int nb4 = (N + 3) / 4;
    k_xform1<<<nb4, 256, 0, stream>>>(x, topo, W1, a_s1, a_d1, h1, as1, ad1, N);
    k_agg1<<<nb4, 256, 0, stream>>>(h1, as1, ad1, b1, rowptr, csr, h2, N);
    k_xform2<<<nb4, 256, 0, stream>>>(h2, W2, a_s2, a_d2, gbuf, as2, ad2, N);
    k_agg2<<<nb4, 256, 0, stream>>>(gbuf, as2, ad2, b2, rowptr, csr, out, N);
}

// Round 2
// 758.428 us; speedup vs baseline: 1.2605x; 1.2605x over previous
//
#include <hip/hip_runtime.h>
#include <math.h>

// ---------------------------------------------------------------------------
// TopoGAT: 2-layer GAT on MI355X.
// Pipeline: deg-histogram -> exclusive scan -> CSR fill (by dst) ->
//   xform1 (h1 = [x|topo]@W1, alpha_src/dst per head) ->
//   agg1   (per-dst softmax-weighted gather, ELU) ->
//   xform2 (g = h2@W2, alpha scalars) ->
//   agg2   (gather + log_softmax) -> d_out.
// R1: xform kernels register-blocked (8 nodes/wave): W read from LDS once per
// 8 FMAs, x-row broadcasts via wave-uniform (SGPR) loads -> off the LDS pipe.
// ---------------------------------------------------------------------------

__global__ void k_zero_i32(int* __restrict__ p, int n) {
    int i = blockIdx.x * blockDim.x + threadIdx.x;
    if (i < n) p[i] = 0;
}

__global__ void k_hist(const int* __restrict__ dst, int* __restrict__ deg, int E) {
    int e = blockIdx.x * blockDim.x + threadIdx.x;
    if (e < E) atomicAdd(&deg[dst[e]], 1);
}

// Block scans 1024 elements (256 threads x 4). Writes per-element exclusive
// prefix (block-local) to rowptr and block total to partials[blk].
__global__ __launch_bounds__(256) void k_scan1(const int* __restrict__ deg,
                                               int* __restrict__ rowptr,
                                               int* __restrict__ partials, int N) {
    __shared__ int wsum[4];
    int tid = threadIdx.x, lane = tid & 63, wv = tid >> 6;
    int base = blockIdx.x * 1024 + tid * 4;
    int d0 = (base + 0 < N) ? deg[base + 0] : 0;
    int d1 = (base + 1 < N) ? deg[base + 1] : 0;
    int d2 = (base + 2 < N) ? deg[base + 2] : 0;
    int d3 = (base + 3 < N) ? deg[base + 3] : 0;
    int tsum = d0 + d1 + d2 + d3;
    int v = tsum;
    #pragma unroll
    for (int ofs = 1; ofs < 64; ofs <<= 1) {
        int t = __shfl_up(v, ofs);
        if (lane >= ofs) v += t;
    }
    if (lane == 63) wsum[wv] = v;
    __syncthreads();
    int woff = 0;
    for (int i = 0; i < wv; i++) woff += wsum[i];
    int ex = woff + v - tsum;  // exclusive prefix for this thread
    if (base + 0 < N) rowptr[base + 0] = ex;
    if (base + 1 < N) rowptr[base + 1] = ex + d0;
    if (base + 2 < N) rowptr[base + 2] = ex + d0 + d1;
    if (base + 3 < N) rowptr[base + 3] = ex + d0 + d1 + d2;
    if (tid == 255) partials[blockIdx.x] = woff + v;  // block total
}

// Single block exclusive-scans partials (NB <= 128).
__global__ __launch_bounds__(128) void k_scan2(int* __restrict__ partials, int NB) {
    __shared__ int wsum[2];
    int tid = threadIdx.x, lane = tid & 63, wv = tid >> 6;
    int p = (tid < NB) ? partials[tid] : 0;
    int v = p;
    #pragma unroll
    for (int ofs = 1; ofs < 64; ofs <<= 1) {
        int t = __shfl_up(v, ofs);
        if (lane >= ofs) v += t;
    }
    if (lane == 63) wsum[wv] = v;
    __syncthreads();
    int wo = (wv == 1) ? wsum[0] : 0;
    if (tid < NB) partials[tid] = wo + v - p;
}

__global__ void k_scan3(int* __restrict__ rowptr, int* __restrict__ cursor,
                        const int* __restrict__ partials, int N, int E) {
    int i = blockIdx.x * blockDim.x + threadIdx.x;
    if (i < N) {
        int r = rowptr[i] + partials[i >> 10];
        rowptr[i] = r;
        cursor[i] = r;
    }
    if (i == N) rowptr[N] = E;
}

__global__ void k_fill(const int* __restrict__ src, const int* __restrict__ dst,
                       int* __restrict__ cursor, int* __restrict__ csr, int E) {
    int e = blockIdx.x * blockDim.x + threadIdx.x;
    if (e < E) {
        int p = atomicAdd(&cursor[dst[e]], 1);
        csr[p] = src[e];
    }
}

// h1[n][64] = [x[n]|topo[n]] @ W1 ; as1[n][8], ad1[n][8] head-wise dots.
// One wave computes 8 nodes; lane = output column (head = lane>>3, chan = lane&7).
// W read from LDS once per k-step (reused 8x); x values are wave-uniform
// scalar loads (node index forced to SGPR) -> SMEM pipe, not LDS pipe.
__global__ __launch_bounds__(256) void k_xform1(const float* __restrict__ x,
                                                const float* __restrict__ topo,
                                                const float* __restrict__ W1,
                                                const float* __restrict__ asrc,
                                                const float* __restrict__ adst,
                                                float* __restrict__ h1,
                                                float* __restrict__ as1,
                                                float* __restrict__ ad1, int N) {
    __shared__ float Wl[136 * 64];
    __shared__ float asl[64], adl[64];
    int tid = threadIdx.x;
    {   // vectorized W1 stage: 8704 floats = 2176 float4
        const float4* W4 = (const float4*)W1;
        float4* Wl4 = (float4*)Wl;
        for (int i = tid; i < 2176; i += 256) Wl4[i] = W4[i];
    }
    if (tid < 64) { asl[tid] = asrc[tid]; adl[tid] = adst[tid]; }
    __syncthreads();
    int lane = tid & 63;
    int wv = __builtin_amdgcn_readfirstlane(tid >> 6);  // uniform wave id
    int n0 = (blockIdx.x * 4 + wv) * 8;
    if (n0 >= N) return;
    // Wave-uniform row pointers (SGPR) -> scalar loads for x broadcasts.
    const float* xrow[8];
    const float* trow[8];
    #pragma unroll
    for (int i = 0; i < 8; i++) {
        int n = n0 + i; if (n > N - 1) n = N - 1;
        xrow[i] = x + (size_t)n * 128;
        trow[i] = topo + (size_t)n * 8;
    }
    float acc[8];
    #pragma unroll
    for (int i = 0; i < 8; i++) acc[i] = 0.f;
    for (int kc = 0; kc < 128; kc += 4) {
        float w0 = Wl[(kc + 0) * 64 + lane];
        float w1 = Wl[(kc + 1) * 64 + lane];
        float w2 = Wl[(kc + 2) * 64 + lane];
        float w3 = Wl[(kc + 3) * 64 + lane];
        #pragma unroll
        for (int i = 0; i < 8; i++) {
            acc[i] = fmaf(xrow[i][kc + 0], w0, acc[i]);
            acc[i] = fmaf(xrow[i][kc + 1], w1, acc[i]);
            acc[i] = fmaf(xrow[i][kc + 2], w2, acc[i]);
            acc[i] = fmaf(xrow[i][kc + 3], w3, acc[i]);
        }
    }
    #pragma unroll
    for (int j = 0; j < 8; j++) {
        float w = Wl[(128 + j) * 64 + lane];
        #pragma unroll
        for (int i = 0; i < 8; i++) acc[i] = fmaf(trow[i][j], w, acc[i]);
    }
    #pragma unroll
    for (int i = 0; i < 8; i++) {
        int n = n0 + i;
        if (n >= N) break;
        float a = acc[i];
        h1[(size_t)n * 64 + lane] = a;
        float sv = a * asl[lane];
        float dv = a * adl[lane];
        sv += __shfl_xor(sv, 1); sv += __shfl_xor(sv, 2); sv += __shfl_xor(sv, 4);
        dv += __shfl_xor(dv, 1); dv += __shfl_xor(dv, 2); dv += __shfl_xor(dv, 4);
        if ((lane & 7) == 0) {
            as1[n * 8 + (lane >> 3)] = sv;
            ad1[n * 8 + (lane >> 3)] = dv;
        }
    }
}

// Per-dst softmax-weighted aggregation over in-edges (+ implicit self loop).
__global__ __launch_bounds__(256) void k_agg1(const float* __restrict__ h1,
                                              const float* __restrict__ as1,
                                              const float* __restrict__ ad1,
                                              const float* __restrict__ b1,
                                              const int* __restrict__ rowptr,
                                              const int* __restrict__ csr,
                                              float* __restrict__ h2, int N) {
    int tid = threadIdx.x, lane = tid & 63;
    int n = blockIdx.x * 4 + (tid >> 6);
    if (n >= N) return;
    int myh = lane >> 3;
    float ad_d = ad1[n * 8 + myh];
    // self loop (src == dst == n)
    float e0 = as1[n * 8 + myh] + ad_d;
    float w = __expf(e0 >= 0.f ? e0 : 0.2f * e0);
    float acc = w * h1[n * 64 + lane];
    float z = w;
    int j0 = rowptr[n], j1 = rowptr[n + 1];
    for (int j = j0; j < j1; ++j) {
        int s = csr[j];
        float e = as1[s * 8 + myh] + ad_d;
        float ww = __expf(e >= 0.f ? e : 0.2f * e);
        acc = fmaf(ww, h1[s * 64 + lane], acc);
        z += ww;
    }
    float v = acc / (z + 1e-16f) + b1[lane];
    h2[n * 64 + lane] = v > 0.f ? v : (__expf(v) - 1.f);  // ELU
}

// g[n][40] = h2[n] @ W2 ; scalar attention dots as2[n], ad2[n].
// Same 8-nodes-per-wave register blocking as k_xform1.
__global__ __launch_bounds__(256) void k_xform2(const float* __restrict__ h2,
                                                const float* __restrict__ W2,
                                                const float* __restrict__ asrc2,
                                                const float* __restrict__ adst2,
                                                float* __restrict__ g,
                                                float* __restrict__ as2,
                                                float* __restrict__ ad2, int N) {
    __shared__ float Wl[64 * 40];
    __shared__ float asl[40], adl[40];
    int tid = threadIdx.x;
    {   // 2560 floats = 640 float4
        const float4* W4 = (const float4*)W2;
        float4* Wl4 = (float4*)Wl;
        for (int i = tid; i < 640; i += 256) Wl4[i] = W4[i];
    }
    if (tid < 40) { asl[tid] = asrc2[tid]; adl[tid] = adst2[tid]; }
    __syncthreads();
    int lane = tid & 63;
    int wv = __builtin_amdgcn_readfirstlane(tid >> 6);
    int n0 = (blockIdx.x * 4 + wv) * 8;
    if (n0 >= N) return;
    int c = (lane < 40) ? lane : 0;  // clamp idle lanes in-bounds
    const float* hrow[8];
    #pragma unroll
    for (int i = 0; i < 8; i++) {
        int n = n0 + i; if (n > N - 1) n = N - 1;
        hrow[i] = h2 + (size_t)n * 64;
    }
    float acc[8];
    #pragma unroll
    for (int i = 0; i < 8; i++) acc[i] = 0.f;
    for (int kc = 0; kc < 64; kc += 4) {
        float w0 = Wl[(kc + 0) * 40 + c];
        float w1 = Wl[(kc + 1) * 40 + c];
        float w2 = Wl[(kc + 2) * 40 + c];
        float w3 = Wl[(kc + 3) * 40 + c];
        #pragma unroll
        for (int i = 0; i < 8; i++) {
            acc[i] = fmaf(hrow[i][kc + 0], w0, acc[i]);
            acc[i] = fmaf(hrow[i][kc + 1], w1, acc[i]);
            acc[i] = fmaf(hrow[i][kc + 2], w2, acc[i]);
            acc[i] = fmaf(hrow[i][kc + 3], w3, acc[i]);
        }
    }
    #pragma unroll
    for (int i = 0; i < 8; i++) {
        int n = n0 + i;
        if (n >= N) break;
        float a = acc[i];
        float sv = (lane < 40) ? a * asl[c] : 0.f;
        float dv = (lane < 40) ? a * adl[c] : 0.f;
        #pragma unroll
        for (int ofs = 1; ofs < 64; ofs <<= 1) {
            sv += __shfl_xor(sv, ofs);
            dv += __shfl_xor(dv, ofs);
        }
        if (lane == 0) { as2[n] = sv; ad2[n] = dv; }
        if (lane < 40) g[n * 40 + lane] = a;
    }
}

// Layer-2 aggregation + bias + log_softmax.
__global__ __launch_bounds__(256) void k_agg2(const float* __restrict__ g,
                                              const float* __restrict__ as2,
                                              const float* __restrict__ ad2,
                                              const float* __restrict__ b2,
                                              const int* __restrict__ rowptr,
                                              const int* __restrict__ csr,
                                              float* __restrict__ out, int N) {
    int tid = threadIdx.x, lane = tid & 63;
    int n = blockIdx.x * 4 + (tid >> 6);
    if (n >= N) return;
    int c = (lane < 40) ? lane : 0;
    float add = ad2[n];
    float e0 = as2[n] + add;
    float w = __expf(e0 >= 0.f ? e0 : 0.2f * e0);
    float acc = w * g[n * 40 + c];
    float z = w;
    int j0 = rowptr[n], j1 = rowptr[n + 1];
    for (int j = j0; j < j1; ++j) {
        int s = csr[j];
        float e = as2[s] + add;
        float ww = __expf(e >= 0.f ? e : 0.2f * e);
        acc = fmaf(ww, g[s * 40 + c], acc);
        z += ww;
    }
    float logit = acc / (z + 1e-16f) + b2[c];
    float mv = (lane < 40) ? logit : -INFINITY;
    #pragma unroll
    for (int ofs = 1; ofs < 64; ofs <<= 1) mv = fmaxf(mv, __shfl_xor(mv, ofs));
    float ev = (lane < 40) ? __expf(logit - mv) : 0.f;
    #pragma unroll
    for (int ofs = 1; ofs < 64; ofs <<= 1) ev += __shfl_xor(ev, ofs);
    if (lane < 40) out[n * 40 + lane] = logit - mv - __logf(ev);
}

extern "C" void kernel_launch(void* const* d_in, const int* in_sizes, int n_in,
                              void* d_out, int out_size, void* d_ws, size_t ws_size,
                              hipStream_t stream) {
    const float* x    = (const float*)d_in[0];
    const float* topo = (const float*)d_in[1];
    const int*   ei   = (const int*)d_in[2];
    const float* W1   = (const float*)d_in[3];
    const float* a_s1 = (const float*)d_in[4];
    const float* a_d1 = (const float*)d_in[5];
    const float* b1   = (const float*)d_in[6];
    const float* W2   = (const float*)d_in[7];
    const float* a_s2 = (const float*)d_in[8];
    const float* a_d2 = (const float*)d_in[9];
    const float* b2   = (const float*)d_in[10];
    float* out = (float*)d_out;

    int N = in_sizes[0] / 128;
    int E = in_sizes[2] / 2;
    const int* esrc = ei;
    const int* edst = ei + E;

    char* ws = (char*)d_ws;
    size_t off = 0;
    auto alloc = [&](size_t bytes) -> void* {
        void* p = ws + off;
        off = (off + bytes + 255) & ~(size_t)255;
        return p;
    };
    float* h1     = (float*)alloc((size_t)N * 64 * 4);
    float* as1    = (float*)alloc((size_t)N * 8 * 4);
    float* ad1    = (float*)alloc((size_t)N * 8 * 4);
    float* h2     = (float*)alloc((size_t)N * 64 * 4);
    float* gbuf   = (float*)alloc((size_t)N * 40 * 4);
    float* as2    = (float*)alloc((size_t)N * 4);
    float* ad2    = (float*)alloc((size_t)N * 4);
    int*   deg    = (int*)alloc((size_t)N * 4);
    int*   rowptr = (int*)alloc((size_t)(N + 1) * 4);
    int*   cursor = (int*)alloc((size_t)N * 4);
    int*   csr    = (int*)alloc((size_t)E * 4);
    int NB = (N + 1023) / 1024;
    int*   partials = (int*)alloc((size_t)NB * 4);

    k_zero_i32<<<(N + 255) / 256, 256, 0, stream>>>(deg, N);
    k_hist<<<(E + 255) / 256, 256, 0, stream>>>(edst, deg, E);
    k_scan1<<<NB, 256, 0, stream>>>(deg, rowptr, partials, N);
    k_scan2<<<1, 128, 0, stream>>>(partials, NB);
    k_scan3<<<(N + 1 + 255) / 256, 256, 0, stream>>>(rowptr, cursor, partials, N, E);
    k_fill<<<(E + 255) / 256, 256, 0, stream>>>(esrc, edst, cursor, csr, E);

    int nb32 = (N + 31) / 32;   // 8 nodes/wave x 4 waves/block
    int nb4  = (N + 3) / 4;     // 1 node/wave  x 4 waves/block
    k_xform1<<<nb32, 256, 0, stream>>>(x, topo, W1, a_s1, a_d1, h1, as1, ad1, N);
    k_agg1<<<nb4, 256, 0, stream>>>(h1, as1, ad1, b1, rowptr, csr, h2, N);
    k_xform2<<<nb32, 256, 0, stream>>>(h2, W2, a_s2, a_d2, gbuf, as2, ad2, N);
    k_agg2<<<nb4, 256, 0, stream>>>(gbuf, as2, ad2, b2, rowptr, csr, out, N);
}

// Round 3
// 599.071 us; speedup vs baseline: 1.5958x; 1.2660x over previous
//
#include <hip/hip_runtime.h>
#include <math.h>

// ---------------------------------------------------------------------------
// TopoGAT: 2-layer GAT on MI355X.
// Pipeline: deg-histogram -> exclusive scan -> CSR fill (by dst) ->
//   xform1 (h1 = [x|topo]@W1, alpha_src/dst per head) ->
//   agg1   (per-dst softmax-weighted gather, ELU) ->
//   xform2 (g = h2@W2, alpha scalars) ->
//   agg2   (gather + log_softmax) -> d_out.
// R1: xform kernels register-blocked (8 nodes/wave).
// R2: agg kernels unrolled x8 with batched independent gathers -> 8
//     outstanding 256B row loads per wave (was 1; latency-bound at 2.3 TB/s).
// ---------------------------------------------------------------------------

__global__ void k_hist(const int* __restrict__ dst, int* __restrict__ deg, int E) {
    int e = blockIdx.x * blockDim.x + threadIdx.x;
    if (e < E) atomicAdd(&deg[dst[e]], 1);
}

// Block scans 1024 elements (256 threads x 4). Writes per-element exclusive
// prefix (block-local) to rowptr and block total to partials[blk].
__global__ __launch_bounds__(256) void k_scan1(const int* __restrict__ deg,
                                               int* __restrict__ rowptr,
                                               int* __restrict__ partials, int N) {
    __shared__ int wsum[4];
    int tid = threadIdx.x, lane = tid & 63, wv = tid >> 6;
    int base = blockIdx.x * 1024 + tid * 4;
    int d0 = (base + 0 < N) ? deg[base + 0] : 0;
    int d1 = (base + 1 < N) ? deg[base + 1] : 0;
    int d2 = (base + 2 < N) ? deg[base + 2] : 0;
    int d3 = (base + 3 < N) ? deg[base + 3] : 0;
    int tsum = d0 + d1 + d2 + d3;
    int v = tsum;
    #pragma unroll
    for (int ofs = 1; ofs < 64; ofs <<= 1) {
        int t = __shfl_up(v, ofs);
        if (lane >= ofs) v += t;
    }
    if (lane == 63) wsum[wv] = v;
    __syncthreads();
    int woff = 0;
    for (int i = 0; i < wv; i++) woff += wsum[i];
    int ex = woff + v - tsum;  // exclusive prefix for this thread
    if (base + 0 < N) rowptr[base + 0] = ex;
    if (base + 1 < N) rowptr[base + 1] = ex + d0;
    if (base + 2 < N) rowptr[base + 2] = ex + d0 + d1;
    if (base + 3 < N) rowptr[base + 3] = ex + d0 + d1 + d2;
    if (tid == 255) partials[blockIdx.x] = woff + v;  // block total
}

// Single block exclusive-scans partials (NB <= 128).
__global__ __launch_bounds__(128) void k_scan2(int* __restrict__ partials, int NB) {
    __shared__ int wsum[2];
    int tid = threadIdx.x, lane = tid & 63, wv = tid >> 6;
    int p = (tid < NB) ? partials[tid] : 0;
    int v = p;
    #pragma unroll
    for (int ofs = 1; ofs < 64; ofs <<= 1) {
        int t = __shfl_up(v, ofs);
        if (lane >= ofs) v += t;
    }
    if (lane == 63) wsum[wv] = v;
    __syncthreads();
    int wo = (wv == 1) ? wsum[0] : 0;
    if (tid < NB) partials[tid] = wo + v - p;
}

__global__ void k_scan3(int* __restrict__ rowptr, int* __restrict__ cursor,
                        const int* __restrict__ partials, int N, int E) {
    int i = blockIdx.x * blockDim.x + threadIdx.x;
    if (i < N) {
        int r = rowptr[i] + partials[i >> 10];
        rowptr[i] = r;
        cursor[i] = r;
    }
    if (i == N) rowptr[N] = E;
}

__global__ void k_fill(const int* __restrict__ src, const int* __restrict__ dst,
                       int* __restrict__ cursor, int* __restrict__ csr, int E) {
    int e = blockIdx.x * blockDim.x + threadIdx.x;
    if (e < E) {
        int p = atomicAdd(&cursor[dst[e]], 1);
        csr[p] = src[e];
    }
}

// h1[n][64] = [x[n]|topo[n]] @ W1 ; as1[n][8], ad1[n][8] head-wise dots.
// One wave computes 8 nodes; lane = output column (head = lane>>3, chan = lane&7).
__global__ __launch_bounds__(256) void k_xform1(const float* __restrict__ x,
                                                const float* __restrict__ topo,
                                                const float* __restrict__ W1,
                                                const float* __restrict__ asrc,
                                                const float* __restrict__ adst,
                                                float* __restrict__ h1,
                                                float* __restrict__ as1,
                                                float* __restrict__ ad1, int N) {
    __shared__ float Wl[136 * 64];
    __shared__ float asl[64], adl[64];
    int tid = threadIdx.x;
    {   // vectorized W1 stage: 8704 floats = 2176 float4
        const float4* W4 = (const float4*)W1;
        float4* Wl4 = (float4*)Wl;
        for (int i = tid; i < 2176; i += 256) Wl4[i] = W4[i];
    }
    if (tid < 64) { asl[tid] = asrc[tid]; adl[tid] = adst[tid]; }
    __syncthreads();
    int lane = tid & 63;
    int wv = __builtin_amdgcn_readfirstlane(tid >> 6);  // uniform wave id
    int n0 = (blockIdx.x * 4 + wv) * 8;
    if (n0 >= N) return;
    const float* xrow[8];
    const float* trow[8];
    #pragma unroll
    for (int i = 0; i < 8; i++) {
        int n = n0 + i; if (n > N - 1) n = N - 1;
        xrow[i] = x + (size_t)n * 128;
        trow[i] = topo + (size_t)n * 8;
    }
    float acc[8];
    #pragma unroll
    for (int i = 0; i < 8; i++) acc[i] = 0.f;
    for (int kc = 0; kc < 128; kc += 4) {
        float w0 = Wl[(kc + 0) * 64 + lane];
        float w1 = Wl[(kc + 1) * 64 + lane];
        float w2 = Wl[(kc + 2) * 64 + lane];
        float w3 = Wl[(kc + 3) * 64 + lane];
        #pragma unroll
        for (int i = 0; i < 8; i++) {
            acc[i] = fmaf(xrow[i][kc + 0], w0, acc[i]);
            acc[i] = fmaf(xrow[i][kc + 1], w1, acc[i]);
            acc[i] = fmaf(xrow[i][kc + 2], w2, acc[i]);
            acc[i] = fmaf(xrow[i][kc + 3], w3, acc[i]);
        }
    }
    #pragma unroll
    for (int j = 0; j < 8; j++) {
        float w = Wl[(128 + j) * 64 + lane];
        #pragma unroll
        for (int i = 0; i < 8; i++) acc[i] = fmaf(trow[i][j], w, acc[i]);
    }
    #pragma unroll
    for (int i = 0; i < 8; i++) {
        int n = n0 + i;
        if (n >= N) break;
        float a = acc[i];
        h1[(size_t)n * 64 + lane] = a;
        float sv = a * asl[lane];
        float dv = a * adl[lane];
        sv += __shfl_xor(sv, 1); sv += __shfl_xor(sv, 2); sv += __shfl_xor(sv, 4);
        dv += __shfl_xor(dv, 1); dv += __shfl_xor(dv, 2); dv += __shfl_xor(dv, 4);
        if ((lane & 7) == 0) {
            as1[n * 8 + (lane >> 3)] = sv;
            ad1[n * 8 + (lane >> 3)] = dv;
        }
    }
}

// Per-dst softmax-weighted aggregation over in-edges (+ implicit self loop).
// Edge loop unrolled x8: all 8 row gathers issued before first use -> 8
// outstanding 256B loads/wave (latency hiding).
__global__ __launch_bounds__(256) void k_agg1(const float* __restrict__ h1,
                                              const float* __restrict__ as1,
                                              const float* __restrict__ ad1,
                                              const float* __restrict__ b1,
                                              const int* __restrict__ rowptr,
                                              const int* __restrict__ csr,
                                              float* __restrict__ h2, int N) {
    int tid = threadIdx.x, lane = tid & 63;
    int n = blockIdx.x * 4 + (tid >> 6);
    if (n >= N) return;
    int myh = lane >> 3;
    float ad_d = ad1[n * 8 + myh];
    float e0 = as1[n * 8 + myh] + ad_d;  // self loop
    float w0s = __expf(e0 >= 0.f ? e0 : 0.2f * e0);
    float acc0 = w0s * h1[(size_t)n * 64 + lane], z0 = w0s;
    float acc1 = 0.f, z1 = 0.f, acc2 = 0.f, z2 = 0.f, acc3 = 0.f, z3 = 0.f;
    int j0 = rowptr[n], j1 = rowptr[n + 1];
    int j = j0;
    for (; j + 8 <= j1; j += 8) {
        int s0 = csr[j + 0], s1 = csr[j + 1], s2 = csr[j + 2], s3 = csr[j + 3];
        int s4 = csr[j + 4], s5 = csr[j + 5], s6 = csr[j + 6], s7 = csr[j + 7];
        float f0 = h1[(size_t)s0 * 64 + lane];
        float f1 = h1[(size_t)s1 * 64 + lane];
        float f2 = h1[(size_t)s2 * 64 + lane];
        float f3 = h1[(size_t)s3 * 64 + lane];
        float f4 = h1[(size_t)s4 * 64 + lane];
        float f5 = h1[(size_t)s5 * 64 + lane];
        float f6 = h1[(size_t)s6 * 64 + lane];
        float f7 = h1[(size_t)s7 * 64 + lane];
        float a0 = as1[s0 * 8 + myh], a1 = as1[s1 * 8 + myh];
        float a2 = as1[s2 * 8 + myh], a3 = as1[s3 * 8 + myh];
        float a4 = as1[s4 * 8 + myh], a5 = as1[s5 * 8 + myh];
        float a6 = as1[s6 * 8 + myh], a7 = as1[s7 * 8 + myh];
        float q0 = a0 + ad_d, q1 = a1 + ad_d, q2 = a2 + ad_d, q3 = a3 + ad_d;
        float q4 = a4 + ad_d, q5 = a5 + ad_d, q6 = a6 + ad_d, q7 = a7 + ad_d;
        float w0 = __expf(q0 >= 0.f ? q0 : 0.2f * q0);
        float w1 = __expf(q1 >= 0.f ? q1 : 0.2f * q1);
        float w2 = __expf(q2 >= 0.f ? q2 : 0.2f * q2);
        float w3 = __expf(q3 >= 0.f ? q3 : 0.2f * q3);
        float w4 = __expf(q4 >= 0.f ? q4 : 0.2f * q4);
        float w5 = __expf(q5 >= 0.f ? q5 : 0.2f * q5);
        float w6 = __expf(q6 >= 0.f ? q6 : 0.2f * q6);
        float w7 = __expf(q7 >= 0.f ? q7 : 0.2f * q7);
        acc0 = fmaf(w0, f0, acc0); z0 += w0;
        acc1 = fmaf(w1, f1, acc1); z1 += w1;
        acc2 = fmaf(w2, f2, acc2); z2 += w2;
        acc3 = fmaf(w3, f3, acc3); z3 += w3;
        acc0 = fmaf(w4, f4, acc0); z0 += w4;
        acc1 = fmaf(w5, f5, acc1); z1 += w5;
        acc2 = fmaf(w6, f6, acc2); z2 += w6;
        acc3 = fmaf(w7, f7, acc3); z3 += w7;
    }
    for (; j < j1; ++j) {
        int s = csr[j];
        float e = as1[s * 8 + myh] + ad_d;
        float ww = __expf(e >= 0.f ? e : 0.2f * e);
        acc0 = fmaf(ww, h1[(size_t)s * 64 + lane], acc0);
        z0 += ww;
    }
    float acc = (acc0 + acc1) + (acc2 + acc3);
    float z = (z0 + z1) + (z2 + z3);
    float v = acc / (z + 1e-16f) + b1[lane];
    h2[(size_t)n * 64 + lane] = v > 0.f ? v : (__expf(v) - 1.f);  // ELU
}

// g[n][40] = h2[n] @ W2 ; scalar attention dots as2[n], ad2[n].
__global__ __launch_bounds__(256) void k_xform2(const float* __restrict__ h2,
                                                const float* __restrict__ W2,
                                                const float* __restrict__ asrc2,
                                                const float* __restrict__ adst2,
                                                float* __restrict__ g,
                                                float* __restrict__ as2,
                                                float* __restrict__ ad2, int N) {
    __shared__ float Wl[64 * 40];
    __shared__ float asl[40], adl[40];
    int tid = threadIdx.x;
    {   // 2560 floats = 640 float4
        const float4* W4 = (const float4*)W2;
        float4* Wl4 = (float4*)Wl;
        for (int i = tid; i < 640; i += 256) Wl4[i] = W4[i];
    }
    if (tid < 40) { asl[tid] = asrc2[tid]; adl[tid] = adst2[tid]; }
    __syncthreads();
    int lane = tid & 63;
    int wv = __builtin_amdgcn_readfirstlane(tid >> 6);
    int n0 = (blockIdx.x * 4 + wv) * 8;
    if (n0 >= N) return;
    int c = (lane < 40) ? lane : 0;  // clamp idle lanes in-bounds
    const float* hrow[8];
    #pragma unroll
    for (int i = 0; i < 8; i++) {
        int n = n0 + i; if (n > N - 1) n = N - 1;
        hrow[i] = h2 + (size_t)n * 64;
    }
    float acc[8];
    #pragma unroll
    for (int i = 0; i < 8; i++) acc[i] = 0.f;
    for (int kc = 0; kc < 64; kc += 4) {
        float w0 = Wl[(kc + 0) * 40 + c];
        float w1 = Wl[(kc + 1) * 40 + c];
        float w2 = Wl[(kc + 2) * 40 + c];
        float w3 = Wl[(kc + 3) * 40 + c];
        #pragma unroll
        for (int i = 0; i < 8; i++) {
            acc[i] = fmaf(hrow[i][kc + 0], w0, acc[i]);
            acc[i] = fmaf(hrow[i][kc + 1], w1, acc[i]);
            acc[i] = fmaf(hrow[i][kc + 2], w2, acc[i]);
            acc[i] = fmaf(hrow[i][kc + 3], w3, acc[i]);
        }
    }
    #pragma unroll
    for (int i = 0; i < 8; i++) {
        int n = n0 + i;
        if (n >= N) break;
        float a = acc[i];
        float sv = (lane < 40) ? a * asl[c] : 0.f;
        float dv = (lane < 40) ? a * adl[c] : 0.f;
        #pragma unroll
        for (int ofs = 1; ofs < 64; ofs <<= 1) {
            sv += __shfl_xor(sv, ofs);
            dv += __shfl_xor(dv, ofs);
        }
        if (lane == 0) { as2[n] = sv; ad2[n] = dv; }
        if (lane < 40) g[n * 40 + lane] = a;
    }
}

// Layer-2 aggregation + bias + log_softmax. Edge loop unrolled x8.
__global__ __launch_bounds__(256) void k_agg2(const float* __restrict__ g,
                                              const float* __restrict__ as2,
                                              const float* __restrict__ ad2,
                                              const float* __restrict__ b2,
                                              const int* __restrict__ rowptr,
                                              const int* __restrict__ csr,
                                              float* __restrict__ out, int N) {
    int tid = threadIdx.x, lane = tid & 63;
    int n = blockIdx.x * 4 + (tid >> 6);
    if (n >= N) return;
    int c = (lane < 40) ? lane : 0;
    float add = ad2[n];
    float e0 = as2[n] + add;
    float w0s = __expf(e0 >= 0.f ? e0 : 0.2f * e0);
    float acc0 = w0s * g[(size_t)n * 40 + c], z0 = w0s;
    float acc1 = 0.f, z1 = 0.f, acc2 = 0.f, z2 = 0.f, acc3 = 0.f, z3 = 0.f;
    int j0 = rowptr[n], j1 = rowptr[n + 1];
    int j = j0;
    for (; j + 8 <= j1; j += 8) {
        int s0 = csr[j + 0], s1 = csr[j + 1], s2 = csr[j + 2], s3 = csr[j + 3];
        int s4 = csr[j + 4], s5 = csr[j + 5], s6 = csr[j + 6], s7 = csr[j + 7];
        float f0 = g[(size_t)s0 * 40 + c];
        float f1 = g[(size_t)s1 * 40 + c];
        float f2 = g[(size_t)s2 * 40 + c];
        float f3 = g[(size_t)s3 * 40 + c];
        float f4 = g[(size_t)s4 * 40 + c];
        float f5 = g[(size_t)s5 * 40 + c];
        float f6 = g[(size_t)s6 * 40 + c];
        float f7 = g[(size_t)s7 * 40 + c];
        float a0 = as2[s0], a1 = as2[s1], a2 = as2[s2], a3 = as2[s3];
        float a4 = as2[s4], a5 = as2[s5], a6 = as2[s6], a7 = as2[s7];
        float q0 = a0 + add, q1 = a1 + add, q2 = a2 + add, q3 = a3 + add;
        float q4 = a4 + add, q5 = a5 + add, q6 = a6 + add, q7 = a7 + add;
        float w0 = __expf(q0 >= 0.f ? q0 : 0.2f * q0);
        float w1 = __expf(q1 >= 0.f ? q1 : 0.2f * q1);
        float w2 = __expf(q2 >= 0.f ? q2 : 0.2f * q2);
        float w3 = __expf(q3 >= 0.f ? q3 : 0.2f * q3);
        float w4 = __expf(q4 >= 0.f ? q4 : 0.2f * q4);
        float w5 = __expf(q5 >= 0.f ? q5 : 0.2f * q5);
        float w6 = __expf(q6 >= 0.f ? q6 : 0.2f * q6);
        float w7 = __expf(q7 >= 0.f ? q7 : 0.2f * q7);
        acc0 = fmaf(w0, f0, acc0); z0 += w0;
        acc1 = fmaf(w1, f1, acc1); z1 += w1;
        acc2 = fmaf(w2, f2, acc2); z2 += w2;
        acc3 = fmaf(w3, f3, acc3); z3 += w3;
        acc0 = fmaf(w4, f4, acc0); z0 += w4;
        acc1 = fmaf(w5, f5, acc1); z1 += w5;
        acc2 = fmaf(w6, f6, acc2); z2 += w6;
        acc3 = fmaf(w7, f7, acc3); z3 += w7;
    }
    for (; j < j1; ++j) {
        int s = csr[j];
        float e = as2[s] + add;
        float ww = __expf(e >= 0.f ? e : 0.2f * e);
        acc0 = fmaf(ww, g[(size_t)s * 40 + c], acc0);
        z0 += ww;
    }
    float acc = (acc0 + acc1) + (acc2 + acc3);
    float z = (z0 + z1) + (z2 + z3);
    float logit = acc / (z + 1e-16f) + b2[c];
    float mv = (lane < 40) ? logit : -INFINITY;
    #pragma unroll
    for (int ofs = 1; ofs < 64; ofs <<= 1) mv = fmaxf(mv, __shfl_xor(mv, ofs));
    float ev = (lane < 40) ? __expf(logit - mv) : 0.f;
    #pragma unroll
    for (int ofs = 1; ofs < 64; ofs <<= 1) ev += __shfl_xor(ev, ofs);
    if (lane < 40) out[n * 40 + lane] = logit - mv - __logf(ev);
}

extern "C" void kernel_launch(void* const* d_in, const int* in_sizes, int n_in,
                              void* d_out, int out_size, void* d_ws, size_t ws_size,
                              hipStream_t stream) {
    const float* x    = (const float*)d_in[0];
    const float* topo = (const float*)d_in[1];
    const int*   ei   = (const int*)d_in[2];
    const float* W1   = (const float*)d_in[3];
    const float* a_s1 = (const float*)d_in[4];
    const float* a_d1 = (const float*)d_in[5];
    const float* b1   = (const float*)d_in[6];
    const float* W2   = (const float*)d_in[7];
    const float* a_s2 = (const float*)d_in[8];
    const float* a_d2 = (const float*)d_in[9];
    const float* b2   = (const float*)d_in[10];
    float* out = (float*)d_out;

    int N = in_sizes[0] / 128;
    int E = in_sizes[2] / 2;
    const int* esrc = ei;
    const int* edst = ei + E;

    char* ws = (char*)d_ws;
    size_t off = 0;
    auto alloc = [&](size_t bytes) -> void* {
        void* p = ws + off;
        off = (off + bytes + 255) & ~(size_t)255;
        return p;
    };
    float* h1     = (float*)alloc((size_t)N * 64 * 4);
    float* as1    = (float*)alloc((size_t)N * 8 * 4);
    float* ad1    = (float*)alloc((size_t)N * 8 * 4);
    float* h2     = (float*)alloc((size_t)N * 64 * 4);
    float* gbuf   = (float*)alloc((size_t)N * 40 * 4);
    float* as2    = (float*)alloc((size_t)N * 4);
    float* ad2    = (float*)alloc((size_t)N * 4);
    int*   deg    = (int*)alloc((size_t)N * 4);
    int*   rowptr = (int*)alloc((size_t)(N + 1) * 4);
    int*   cursor = (int*)alloc((size_t)N * 4);
    int*   csr    = (int*)alloc((size_t)E * 4);
    int NB = (N + 1023) / 1024;
    int*   partials = (int*)alloc((size_t)NB * 4);

    hipMemsetAsync(deg, 0, (size_t)N * 4, stream);
    k_hist<<<(E + 255) / 256, 256, 0, stream>>>(edst, deg, E);
    k_scan1<<<NB, 256, 0, stream>>>(deg, rowptr, partials, N);
    k_scan2<<<1, 128, 0, stream>>>(partials, NB);
    k_scan3<<<(N + 1 + 255) / 256, 256, 0, stream>>>(rowptr, cursor, partials, N, E);
    k_fill<<<(E + 255) / 256, 256, 0, stream>>>(esrc, edst, cursor, csr, E);

    int nb32 = (N + 31) / 32;   // 8 nodes/wave x 4 waves/block
    int nb4  = (N + 3) / 4;     // 1 node/wave  x 4 waves/block
    k_xform1<<<nb32, 256, 0, stream>>>(x, topo, W1, a_s1, a_d1, h1, as1, ad1, N);
    k_agg1<<<nb4, 256, 0, stream>>>(h1, as1, ad1, b1, rowptr, csr, h2, N);
    k_xform2<<<nb32, 256, 0, stream>>>(h2, W2, a_s2, a_d2, gbuf, as2, ad2, N);
    k_agg2<<<nb4, 256, 0, stream>>>(gbuf, as2, ad2, b2, rowptr, csr, out, N);
}

// Round 4
// 465.698 us; speedup vs baseline: 2.0529x; 1.2864x over previous
//
#include <hip/hip_runtime.h>
#include <math.h>

// ---------------------------------------------------------------------------
// TopoGAT: 2-layer GAT on MI355X.
// R1: xform kernels register-blocked (8 nodes/wave).
// R2: agg kernels unrolled x8 (8 outstanding row gathers/wave).
// R3: CSR build rewritten as two-level binning. Old k_fill wrote 105 MB to
//     HBM (every scattered 4B store = own 64B line writeback, random XCD).
//     New: bucket = 256 dsts; k_bin reserves contiguous per-bucket runs and
//     k_fill2 scatters only within a block-owned 16KB window -> ~1x writeback.
// ---------------------------------------------------------------------------

#define NBUK_MAX 512
#define BIN_CHUNK 4096

__device__ inline int wave_incl_scan(int v, int lane) {
    #pragma unroll
    for (int ofs = 1; ofs < 64; ofs <<= 1) {
        int t = __shfl_up(v, ofs);
        if (lane >= ofs) v += t;
    }
    return v;
}

// Bucket histogram (bucket = dst>>8), LDS-aggregated.
__global__ __launch_bounds__(256) void k_bhist(const int* __restrict__ dst,
                                               int* __restrict__ bucketCnt,
                                               int E, int NBUK) {
    __shared__ int h[NBUK_MAX];
    int tid = threadIdx.x;
    for (int i = tid; i < NBUK; i += 256) h[i] = 0;
    __syncthreads();
    for (int i = blockIdx.x * 256 + tid; i < E; i += gridDim.x * 256)
        atomicAdd(&h[dst[i] >> 8], 1);
    __syncthreads();
    for (int i = tid; i < NBUK; i += 256) {
        int c = h[i];
        if (c) atomicAdd(&bucketCnt[i], c);
    }
}

// One-wave exclusive scan of bucket counts -> bucketOff, gCursor.
__global__ void k_bscan(const int* __restrict__ bucketCnt,
                        int* __restrict__ bucketOff, int* __restrict__ gCursor,
                        int* __restrict__ rowptr, int N, int E, int NBUK) {
    int lane = threadIdx.x & 63;
    int running = 0;
    for (int base = 0; base < NBUK; base += 64) {
        int idx = base + lane;
        int v = (idx < NBUK) ? bucketCnt[idx] : 0;
        int incl = wave_incl_scan(v, lane);
        int excl = running + incl - v;
        if (idx < NBUK) { bucketOff[idx] = excl; gCursor[idx] = excl; }
        running += __shfl(incl, 63);
    }
    if (lane == 0) { bucketOff[NBUK] = running; rowptr[N] = E; }
}

// Bin edges into bucket-contiguous tmp. One global atomic per (block,bucket);
// packed word = (src<<8) | (dst&255).
__global__ __launch_bounds__(256) void k_bin(const int* __restrict__ src,
                                             const int* __restrict__ dst,
                                             int* __restrict__ gCursor,
                                             unsigned int* __restrict__ tmp,
                                             int E, int NBUK) {
    __shared__ int lcnt[NBUK_MAX];
    __shared__ int lcur[NBUK_MAX];
    int tid = threadIdx.x;
    int base = blockIdx.x * BIN_CHUNK;
    for (int i = tid; i < NBUK; i += 256) lcnt[i] = 0;
    __syncthreads();
    #pragma unroll
    for (int k = 0; k < BIN_CHUNK / 256; k++) {
        int i = base + tid + k * 256;
        if (i < E) atomicAdd(&lcnt[dst[i] >> 8], 1);
    }
    __syncthreads();
    for (int b = tid; b < NBUK; b += 256) {
        int c = lcnt[b];
        lcur[b] = c ? atomicAdd(&gCursor[b], c) : 0;
    }
    __syncthreads();
    #pragma unroll
    for (int k = 0; k < BIN_CHUNK / 256; k++) {
        int i = base + tid + k * 256;
        if (i < E) {
            int d = dst[i];
            int p = atomicAdd(&lcur[d >> 8], 1);
            tmp[p] = ((unsigned int)src[i] << 8) | (unsigned int)(d & 255);
        }
    }
}

// Exact CSR fill within a bucket. Block b owns dsts [b*256, b*256+256) and
// edge range [bucketOff[b], bucketOff[b+1]). Per-dst counts/scan/cursors in
// LDS; csr writes confined to the block's contiguous window.
__global__ __launch_bounds__(256) void k_fill2(const unsigned int* __restrict__ tmp,
                                               const int* __restrict__ bucketOff,
                                               int* __restrict__ rowptr,
                                               int* __restrict__ csr, int N) {
    __shared__ int cnt[256];
    __shared__ int cur[256];
    __shared__ int wsum[4];
    int b = blockIdx.x, tid = threadIdx.x;
    int lane = tid & 63, wv = tid >> 6;
    int e0 = bucketOff[b], e1 = bucketOff[b + 1];
    cnt[tid] = 0;
    __syncthreads();
    for (int i = e0 + tid; i < e1; i += 256)
        atomicAdd(&cnt[tmp[i] & 255u], 1);
    __syncthreads();
    int v = cnt[tid];
    int incl = wave_incl_scan(v, lane);
    if (lane == 63) wsum[wv] = incl;
    __syncthreads();
    int woff = 0;
    for (int i = 0; i < wv; i++) woff += wsum[i];
    int excl = woff + incl - v;
    int node = b * 256 + tid;
    if (node < N) rowptr[node] = e0 + excl;
    cur[tid] = e0 + excl;
    __syncthreads();
    for (int i = e0 + tid; i < e1; i += 256) {
        unsigned int t = tmp[i];
        int p = atomicAdd(&cur[t & 255u], 1);
        csr[p] = (int)(t >> 8);
    }
}

// h1[n][64] = [x[n]|topo[n]] @ W1 ; as1[n][8], ad1[n][8] head-wise dots.
// One wave computes 8 nodes; lane = output column (head = lane>>3, chan = lane&7).
__global__ __launch_bounds__(256) void k_xform1(const float* __restrict__ x,
                                                const float* __restrict__ topo,
                                                const float* __restrict__ W1,
                                                const float* __restrict__ asrc,
                                                const float* __restrict__ adst,
                                                float* __restrict__ h1,
                                                float* __restrict__ as1,
                                                float* __restrict__ ad1, int N) {
    __shared__ float Wl[136 * 64];
    __shared__ float asl[64], adl[64];
    int tid = threadIdx.x;
    {   // vectorized W1 stage: 8704 floats = 2176 float4
        const float4* W4 = (const float4*)W1;
        float4* Wl4 = (float4*)Wl;
        for (int i = tid; i < 2176; i += 256) Wl4[i] = W4[i];
    }
    if (tid < 64) { asl[tid] = asrc[tid]; adl[tid] = adst[tid]; }
    __syncthreads();
    int lane = tid & 63;
    int wv = __builtin_amdgcn_readfirstlane(tid >> 6);  // uniform wave id
    int n0 = (blockIdx.x * 4 + wv) * 8;
    if (n0 >= N) return;
    const float* xrow[8];
    const float* trow[8];
    #pragma unroll
    for (int i = 0; i < 8; i++) {
        int n = n0 + i; if (n > N - 1) n = N - 1;
        xrow[i] = x + (size_t)n * 128;
        trow[i] = topo + (size_t)n * 8;
    }
    float acc[8];
    #pragma unroll
    for (int i = 0; i < 8; i++) acc[i] = 0.f;
    for (int kc = 0; kc < 128; kc += 4) {
        float w0 = Wl[(kc + 0) * 64 + lane];
        float w1 = Wl[(kc + 1) * 64 + lane];
        float w2 = Wl[(kc + 2) * 64 + lane];
        float w3 = Wl[(kc + 3) * 64 + lane];
        #pragma unroll
        for (int i = 0; i < 8; i++) {
            acc[i] = fmaf(xrow[i][kc + 0], w0, acc[i]);
            acc[i] = fmaf(xrow[i][kc + 1], w1, acc[i]);
            acc[i] = fmaf(xrow[i][kc + 2], w2, acc[i]);
            acc[i] = fmaf(xrow[i][kc + 3], w3, acc[i]);
        }
    }
    #pragma unroll
    for (int j = 0; j < 8; j++) {
        float w = Wl[(128 + j) * 64 + lane];
        #pragma unroll
        for (int i = 0; i < 8; i++) acc[i] = fmaf(trow[i][j], w, acc[i]);
    }
    #pragma unroll
    for (int i = 0; i < 8; i++) {
        int n = n0 + i;
        if (n >= N) break;
        float a = acc[i];
        h1[(size_t)n * 64 + lane] = a;
        float sv = a * asl[lane];
        float dv = a * adl[lane];
        sv += __shfl_xor(sv, 1); sv += __shfl_xor(sv, 2); sv += __shfl_xor(sv, 4);
        dv += __shfl_xor(dv, 1); dv += __shfl_xor(dv, 2); dv += __shfl_xor(dv, 4);
        if ((lane & 7) == 0) {
            as1[n * 8 + (lane >> 3)] = sv;
            ad1[n * 8 + (lane >> 3)] = dv;
        }
    }
}

// Per-dst softmax-weighted aggregation over in-edges (+ implicit self loop).
// Edge loop unrolled x8: 8 outstanding 256B row gathers per wave.
__global__ __launch_bounds__(256) void k_agg1(const float* __restrict__ h1,
                                              const float* __restrict__ as1,
                                              const float* __restrict__ ad1,
                                              const float* __restrict__ b1,
                                              const int* __restrict__ rowptr,
                                              const int* __restrict__ csr,
                                              float* __restrict__ h2, int N) {
    int tid = threadIdx.x, lane = tid & 63;
    int n = blockIdx.x * 4 + (tid >> 6);
    if (n >= N) return;
    int myh = lane >> 3;
    float ad_d = ad1[n * 8 + myh];
    float e0 = as1[n * 8 + myh] + ad_d;  // self loop
    float w0s = __expf(e0 >= 0.f ? e0 : 0.2f * e0);
    float acc0 = w0s * h1[(size_t)n * 64 + lane], z0 = w0s;
    float acc1 = 0.f, z1 = 0.f, acc2 = 0.f, z2 = 0.f, acc3 = 0.f, z3 = 0.f;
    int j0 = rowptr[n], j1 = rowptr[n + 1];
    int j = j0;
    for (; j + 8 <= j1; j += 8) {
        int s0 = csr[j + 0], s1 = csr[j + 1], s2 = csr[j + 2], s3 = csr[j + 3];
        int s4 = csr[j + 4], s5 = csr[j + 5], s6 = csr[j + 6], s7 = csr[j + 7];
        float f0 = h1[(size_t)s0 * 64 + lane];
        float f1 = h1[(size_t)s1 * 64 + lane];
        float f2 = h1[(size_t)s2 * 64 + lane];
        float f3 = h1[(size_t)s3 * 64 + lane];
        float f4 = h1[(size_t)s4 * 64 + lane];
        float f5 = h1[(size_t)s5 * 64 + lane];
        float f6 = h1[(size_t)s6 * 64 + lane];
        float f7 = h1[(size_t)s7 * 64 + lane];
        float a0 = as1[s0 * 8 + myh], a1 = as1[s1 * 8 + myh];
        float a2 = as1[s2 * 8 + myh], a3 = as1[s3 * 8 + myh];
        float a4 = as1[s4 * 8 + myh], a5 = as1[s5 * 8 + myh];
        float a6 = as1[s6 * 8 + myh], a7 = as1[s7 * 8 + myh];
        float q0 = a0 + ad_d, q1 = a1 + ad_d, q2 = a2 + ad_d, q3 = a3 + ad_d;
        float q4 = a4 + ad_d, q5 = a5 + ad_d, q6 = a6 + ad_d, q7 = a7 + ad_d;
        float w0 = __expf(q0 >= 0.f ? q0 : 0.2f * q0);
        float w1 = __expf(q1 >= 0.f ? q1 : 0.2f * q1);
        float w2 = __expf(q2 >= 0.f ? q2 : 0.2f * q2);
        float w3 = __expf(q3 >= 0.f ? q3 : 0.2f * q3);
        float w4 = __expf(q4 >= 0.f ? q4 : 0.2f * q4);
        float w5 = __expf(q5 >= 0.f ? q5 : 0.2f * q5);
        float w6 = __expf(q6 >= 0.f ? q6 : 0.2f * q6);
        float w7 = __expf(q7 >= 0.f ? q7 : 0.2f * q7);
        acc0 = fmaf(w0, f0, acc0); z0 += w0;
        acc1 = fmaf(w1, f1, acc1); z1 += w1;
        acc2 = fmaf(w2, f2, acc2); z2 += w2;
        acc3 = fmaf(w3, f3, acc3); z3 += w3;
        acc0 = fmaf(w4, f4, acc0); z0 += w4;
        acc1 = fmaf(w5, f5, acc1); z1 += w5;
        acc2 = fmaf(w6, f6, acc2); z2 += w6;
        acc3 = fmaf(w7, f7, acc3); z3 += w7;
    }
    for (; j < j1; ++j) {
        int s = csr[j];
        float e = as1[s * 8 + myh] + ad_d;
        float ww = __expf(e >= 0.f ? e : 0.2f * e);
        acc0 = fmaf(ww, h1[(size_t)s * 64 + lane], acc0);
        z0 += ww;
    }
    float acc = (acc0 + acc1) + (acc2 + acc3);
    float z = (z0 + z1) + (z2 + z3);
    float v = acc / (z + 1e-16f) + b1[lane];
    h2[(size_t)n * 64 + lane] = v > 0.f ? v : (__expf(v) - 1.f);  // ELU
}

// g[n][40] = h2[n] @ W2 ; scalar attention dots as2[n], ad2[n].
__global__ __launch_bounds__(256) void k_xform2(const float* __restrict__ h2,
                                                const float* __restrict__ W2,
                                                const float* __restrict__ asrc2,
                                                const float* __restrict__ adst2,
                                                float* __restrict__ g,
                                                float* __restrict__ as2,
                                                float* __restrict__ ad2, int N) {
    __shared__ float Wl[64 * 40];
    __shared__ float asl[40], adl[40];
    int tid = threadIdx.x;
    {   // 2560 floats = 640 float4
        const float4* W4 = (const float4*)W2;
        float4* Wl4 = (float4*)Wl;
        for (int i = tid; i < 640; i += 256) Wl4[i] = W4[i];
    }
    if (tid < 40) { asl[tid] = asrc2[tid]; adl[tid] = adst2[tid]; }
    __syncthreads();
    int lane = tid & 63;
    int wv = __builtin_amdgcn_readfirstlane(tid >> 6);
    int n0 = (blockIdx.x * 4 + wv) * 8;
    if (n0 >= N) return;
    int c = (lane < 40) ? lane : 0;  // clamp idle lanes in-bounds
    const float* hrow[8];
    #pragma unroll
    for (int i = 0; i < 8; i++) {
        int n = n0 + i; if (n > N - 1) n = N - 1;
        hrow[i] = h2 + (size_t)n * 64;
    }
    float acc[8];
    #pragma unroll
    for (int i = 0; i < 8; i++) acc[i] = 0.f;
    for (int kc = 0; kc < 64; kc += 4) {
        float w0 = Wl[(kc + 0) * 40 + c];
        float w1 = Wl[(kc + 1) * 40 + c];
        float w2 = Wl[(kc + 2) * 40 + c];
        float w3 = Wl[(kc + 3) * 40 + c];
        #pragma unroll
        for (int i = 0; i < 8; i++) {
            acc[i] = fmaf(hrow[i][kc + 0], w0, acc[i]);
            acc[i] = fmaf(hrow[i][kc + 1], w1, acc[i]);
            acc[i] = fmaf(hrow[i][kc + 2], w2, acc[i]);
            acc[i] = fmaf(hrow[i][kc + 3], w3, acc[i]);
        }
    }
    #pragma unroll
    for (int i = 0; i < 8; i++) {
        int n = n0 + i;
        if (n >= N) break;
        float a = acc[i];
        float sv = (lane < 40) ? a * asl[c] : 0.f;
        float dv = (lane < 40) ? a * adl[c] : 0.f;
        #pragma unroll
        for (int ofs = 1; ofs < 64; ofs <<= 1) {
            sv += __shfl_xor(sv, ofs);
            dv += __shfl_xor(dv, ofs);
        }
        if (lane == 0) { as2[n] = sv; ad2[n] = dv; }
        if (lane < 40) g[n * 40 + lane] = a;
    }
}

// Layer-2 aggregation + bias + log_softmax. Edge loop unrolled x8.
__global__ __launch_bounds__(256) void k_agg2(const float* __restrict__ g,
                                              const float* __restrict__ as2,
                                              const float* __restrict__ ad2,
                                              const float* __restrict__ b2,
                                              const int* __restrict__ rowptr,
                                              const int* __restrict__ csr,
                                              float* __restrict__ out, int N) {
    int tid = threadIdx.x, lane = tid & 63;
    int n = blockIdx.x * 4 + (tid >> 6);
    if (n >= N) return;
    int c = (lane < 40) ? lane : 0;
    float add = ad2[n];
    float e0 = as2[n] + add;
    float w0s = __expf(e0 >= 0.f ? e0 : 0.2f * e0);
    float acc0 = w0s * g[(size_t)n * 40 + c], z0 = w0s;
    float acc1 = 0.f, z1 = 0.f, acc2 = 0.f, z2 = 0.f, acc3 = 0.f, z3 = 0.f;
    int j0 = rowptr[n], j1 = rowptr[n + 1];
    int j = j0;
    for (; j + 8 <= j1; j += 8) {
        int s0 = csr[j + 0], s1 = csr[j + 1], s2 = csr[j + 2], s3 = csr[j + 3];
        int s4 = csr[j + 4], s5 = csr[j + 5], s6 = csr[j + 6], s7 = csr[j + 7];
        float f0 = g[(size_t)s0 * 40 + c];
        float f1 = g[(size_t)s1 * 40 + c];
        float f2 = g[(size_t)s2 * 40 + c];
        float f3 = g[(size_t)s3 * 40 + c];
        float f4 = g[(size_t)s4 * 40 + c];
        float f5 = g[(size_t)s5 * 40 + c];
        float f6 = g[(size_t)s6 * 40 + c];
        float f7 = g[(size_t)s7 * 40 + c];
        float a0 = as2[s0], a1 = as2[s1], a2 = as2[s2], a3 = as2[s3];
        float a4 = as2[s4], a5 = as2[s5], a6 = as2[s6], a7 = as2[s7];
        float q0 = a0 + add, q1 = a1 + add, q2 = a2 + add, q3 = a3 + add;
        float q4 = a4 + add, q5 = a5 + add, q6 = a6 + add, q7 = a7 + add;
        float w0 = __expf(q0 >= 0.f ? q0 : 0.2f * q0);
        float w1 = __expf(q1 >= 0.f ? q1 : 0.2f * q1);
        float w2 = __expf(q2 >= 0.f ? q2 : 0.2f * q2);
        float w3 = __expf(q3 >= 0.f ? q3 : 0.2f * q3);
        float w4 = __expf(q4 >= 0.f ? q4 : 0.2f * q4);
        float w5 = __expf(q5 >= 0.f ? q5 : 0.2f * q5);
        float w6 = __expf(q6 >= 0.f ? q6 : 0.2f * q6);
        float w7 = __expf(q7 >= 0.f ? q7 : 0.2f * q7);
        acc0 = fmaf(w0, f0, acc0); z0 += w0;
        acc1 = fmaf(w1, f1, acc1); z1 += w1;
        acc2 = fmaf(w2, f2, acc2); z2 += w2;
        acc3 = fmaf(w3, f3, acc3); z3 += w3;
        acc0 = fmaf(w4, f4, acc0); z0 += w4;
        acc1 = fmaf(w5, f5, acc1); z1 += w5;
        acc2 = fmaf(w6, f6, acc2); z2 += w6;
        acc3 = fmaf(w7, f7, acc3); z3 += w7;
    }
    for (; j < j1; ++j) {
        int s = csr[j];
        float e = as2[s] + add;
        float ww = __expf(e >= 0.f ? e : 0.2f * e);
        acc0 = fmaf(ww, g[(size_t)s * 40 + c], acc0);
        z0 += ww;
    }
    float acc = (acc0 + acc1) + (acc2 + acc3);
    float z = (z0 + z1) + (z2 + z3);
    float logit = acc / (z + 1e-16f) + b2[c];
    float mv = (lane < 40) ? logit : -INFINITY;
    #pragma unroll
    for (int ofs = 1; ofs < 64; ofs <<= 1) mv = fmaxf(mv, __shfl_xor(mv, ofs));
    float ev = (lane < 40) ? __expf(logit - mv) : 0.f;
    #pragma unroll
    for (int ofs = 1; ofs < 64; ofs <<= 1) ev += __shfl_xor(ev, ofs);
    if (lane < 40) out[n * 40 + lane] = logit - mv - __logf(ev);
}

extern "C" void kernel_launch(void* const* d_in, const int* in_sizes, int n_in,
                              void* d_out, int out_size, void* d_ws, size_t ws_size,
                              hipStream_t stream) {
    const float* x    = (const float*)d_in[0];
    const float* topo = (const float*)d_in[1];
    const int*   ei   = (const int*)d_in[2];
    const float* W1   = (const float*)d_in[3];
    const float* a_s1 = (const float*)d_in[4];
    const float* a_d1 = (const float*)d_in[5];
    const float* b1   = (const float*)d_in[6];
    const float* W2   = (const float*)d_in[7];
    const float* a_s2 = (const float*)d_in[8];
    const float* a_d2 = (const float*)d_in[9];
    const float* b2   = (const float*)d_in[10];
    float* out = (float*)d_out;

    int N = in_sizes[0] / 128;
    int E = in_sizes[2] / 2;
    const int* esrc = ei;
    const int* edst = ei + E;
    int NBUK = (N + 255) / 256;

    char* ws = (char*)d_ws;
    size_t off = 0;
    auto alloc = [&](size_t bytes) -> void* {
        void* p = ws + off;
        off = (off + bytes + 255) & ~(size_t)255;
        return p;
    };
    float* h1     = (float*)alloc((size_t)N * 64 * 4);
    float* as1    = (float*)alloc((size_t)N * 8 * 4);
    float* ad1    = (float*)alloc((size_t)N * 8 * 4);
    float* h2     = (float*)alloc((size_t)N * 64 * 4);
    float* gbuf   = (float*)alloc((size_t)N * 40 * 4);
    float* as2    = (float*)alloc((size_t)N * 4);
    float* ad2    = (float*)alloc((size_t)N * 4);
    int*   rowptr = (int*)alloc((size_t)(N + 1) * 4);
    int*   csr    = (int*)alloc((size_t)E * 4);
    unsigned int* tmp = (unsigned int*)alloc((size_t)E * 4);
    int* bucketCnt = (int*)alloc((size_t)(NBUK + 1) * 4);
    int* bucketOff = (int*)alloc((size_t)(NBUK + 1) * 4);
    int* gCursor   = (int*)alloc((size_t)NBUK * 4);

    hipMemsetAsync(bucketCnt, 0, (size_t)(NBUK + 1) * 4, stream);
    k_bhist<<<256, 256, 0, stream>>>(edst, bucketCnt, E, NBUK);
    k_bscan<<<1, 64, 0, stream>>>(bucketCnt, bucketOff, gCursor, rowptr, N, E, NBUK);
    int nbin = (E + BIN_CHUNK - 1) / BIN_CHUNK;
    k_bin<<<nbin, 256, 0, stream>>>(esrc, edst, gCursor, tmp, E, NBUK);
    k_fill2<<<NBUK, 256, 0, stream>>>(tmp, bucketOff, rowptr, csr, N);

    int nb32 = (N + 31) / 32;   // 8 nodes/wave x 4 waves/block
    int nb4  = (N + 3) / 4;     // 1 node/wave  x 4 waves/block
    k_xform1<<<nb32, 256, 0, stream>>>(x, topo, W1, a_s1, a_d1, h1, as1, ad1, N);
    k_agg1<<<nb4, 256, 0, stream>>>(h1, as1, ad1, b1, rowptr, csr, h2, N);
    k_xform2<<<nb32, 256, 0, stream>>>(h2, W2, a_s2, a_d2, gbuf, as2, ad2, N);
    k_agg2<<<nb4, 256, 0, stream>>>(gbuf, as2, ad2, b2, rowptr, csr, out, N);
}

// Round 5
// 428.923 us; speedup vs baseline: 2.2289x; 1.0857x over previous
//
#include <hip/hip_runtime.h>
#include <math.h>

// ---------------------------------------------------------------------------
// TopoGAT: 2-layer GAT on MI355X.
// R2: agg kernels unrolled x8 (8 outstanding row gathers/wave).
// R3: CSR build via two-level binning (write-locality; ~1x writeback).
// R4: xform kernels re-inverted: thread = node, acc[64]/acc[40] in VGPRs.
//     x row: per-thread float4 global loads (vmcnt pipelined, prefetch);
//     W: thread-uniform indices -> s_load to SGPRs (L2-hot), v_fmac s-operand.
//     No LDS, no shfl -> removes the SMEM/LDS lgkmcnt entanglement that held
//     R1's k_xform1 at 16% VALUBusy.
// ---------------------------------------------------------------------------

#define NBUK_MAX 512
#define BIN_CHUNK 4096

__device__ inline int wave_incl_scan(int v, int lane) {
    #pragma unroll
    for (int ofs = 1; ofs < 64; ofs <<= 1) {
        int t = __shfl_up(v, ofs);
        if (lane >= ofs) v += t;
    }
    return v;
}

// Bucket histogram (bucket = dst>>8), LDS-aggregated.
__global__ __launch_bounds__(256) void k_bhist(const int* __restrict__ dst,
                                               int* __restrict__ bucketCnt,
                                               int E, int NBUK) {
    __shared__ int h[NBUK_MAX];
    int tid = threadIdx.x;
    for (int i = tid; i < NBUK; i += 256) h[i] = 0;
    __syncthreads();
    for (int i = blockIdx.x * 256 + tid; i < E; i += gridDim.x * 256)
        atomicAdd(&h[dst[i] >> 8], 1);
    __syncthreads();
    for (int i = tid; i < NBUK; i += 256) {
        int c = h[i];
        if (c) atomicAdd(&bucketCnt[i], c);
    }
}

// One-wave exclusive scan of bucket counts -> bucketOff, gCursor.
__global__ void k_bscan(const int* __restrict__ bucketCnt,
                        int* __restrict__ bucketOff, int* __restrict__ gCursor,
                        int* __restrict__ rowptr, int N, int E, int NBUK) {
    int lane = threadIdx.x & 63;
    int running = 0;
    for (int base = 0; base < NBUK; base += 64) {
        int idx = base + lane;
        int v = (idx < NBUK) ? bucketCnt[idx] : 0;
        int incl = wave_incl_scan(v, lane);
        int excl = running + incl - v;
        if (idx < NBUK) { bucketOff[idx] = excl; gCursor[idx] = excl; }
        running += __shfl(incl, 63);
    }
    if (lane == 0) { bucketOff[NBUK] = running; rowptr[N] = E; }
}

// Bin edges into bucket-contiguous tmp. One global atomic per (block,bucket);
// packed word = (src<<8) | (dst&255).
__global__ __launch_bounds__(256) void k_bin(const int* __restrict__ src,
                                             const int* __restrict__ dst,
                                             int* __restrict__ gCursor,
                                             unsigned int* __restrict__ tmp,
                                             int E, int NBUK) {
    __shared__ int lcnt[NBUK_MAX];
    __shared__ int lcur[NBUK_MAX];
    int tid = threadIdx.x;
    int base = blockIdx.x * BIN_CHUNK;
    for (int i = tid; i < NBUK; i += 256) lcnt[i] = 0;
    __syncthreads();
    #pragma unroll
    for (int k = 0; k < BIN_CHUNK / 256; k++) {
        int i = base + tid + k * 256;
        if (i < E) atomicAdd(&lcnt[dst[i] >> 8], 1);
    }
    __syncthreads();
    for (int b = tid; b < NBUK; b += 256) {
        int c = lcnt[b];
        lcur[b] = c ? atomicAdd(&gCursor[b], c) : 0;
    }
    __syncthreads();
    #pragma unroll
    for (int k = 0; k < BIN_CHUNK / 256; k++) {
        int i = base + tid + k * 256;
        if (i < E) {
            int d = dst[i];
            int p = atomicAdd(&lcur[d >> 8], 1);
            tmp[p] = ((unsigned int)src[i] << 8) | (unsigned int)(d & 255);
        }
    }
}

// Exact CSR fill within a bucket. Block b owns dsts [b*256, b*256+256) and
// edge range [bucketOff[b], bucketOff[b+1]). Per-dst counts/scan/cursors in
// LDS; csr writes confined to the block's contiguous window.
__global__ __launch_bounds__(256) void k_fill2(const unsigned int* __restrict__ tmp,
                                               const int* __restrict__ bucketOff,
                                               int* __restrict__ rowptr,
                                               int* __restrict__ csr, int N) {
    __shared__ int cnt[256];
    __shared__ int cur[256];
    __shared__ int wsum[4];
    int b = blockIdx.x, tid = threadIdx.x;
    int lane = tid & 63, wv = tid >> 6;
    int e0 = bucketOff[b], e1 = bucketOff[b + 1];
    cnt[tid] = 0;
    __syncthreads();
    for (int i = e0 + tid; i < e1; i += 256)
        atomicAdd(&cnt[tmp[i] & 255u], 1);
    __syncthreads();
    int v = cnt[tid];
    int incl = wave_incl_scan(v, lane);
    if (lane == 63) wsum[wv] = incl;
    __syncthreads();
    int woff = 0;
    for (int i = 0; i < wv; i++) woff += wsum[i];
    int excl = woff + incl - v;
    int node = b * 256 + tid;
    if (node < N) rowptr[node] = e0 + excl;
    cur[tid] = e0 + excl;
    __syncthreads();
    for (int i = e0 + tid; i < e1; i += 256) {
        unsigned int t = tmp[i];
        int p = atomicAdd(&cur[t & 255u], 1);
        csr[p] = (int)(t >> 8);
    }
}

// h1[n][64] = [x[n]|topo[n]] @ W1 ; as1[n][8], ad1[n][8] head-wise dots.
// Thread = node. acc[64] in VGPRs; x via per-thread float4 loads (prefetched);
// W accesses thread-uniform -> s_load, v_fmac with SGPR operand.
__global__ __launch_bounds__(256, 4) void k_xform1(const float* __restrict__ x,
                                                   const float* __restrict__ topo,
                                                   const float* __restrict__ W1,
                                                   const float* __restrict__ asrc,
                                                   const float* __restrict__ adst,
                                                   float* __restrict__ h1,
                                                   float* __restrict__ as1,
                                                   float* __restrict__ ad1, int N) {
    int n = blockIdx.x * 256 + threadIdx.x;
    if (n >= N) n = N - 1;  // tail: duplicate compute, identical writes (benign)
    const float4* xr = (const float4*)(x + (size_t)n * 128);
    float acc[64];
    #pragma unroll
    for (int c = 0; c < 64; c++) acc[c] = 0.f;
    float4 xv = xr[0];
    #pragma unroll 1
    for (int k4 = 0; k4 < 32; k4++) {
        float4 cur = xv;
        if (k4 < 31) xv = xr[k4 + 1];  // prefetch next chunk
        const float* Wk = W1 + k4 * 256;  // rows 4k..4k+3 of W1[136][64]
        #pragma unroll
        for (int c = 0; c < 64; c++) acc[c] = fmaf(cur.x, Wk[c], acc[c]);
        #pragma unroll
        for (int c = 0; c < 64; c++) acc[c] = fmaf(cur.y, Wk[64 + c], acc[c]);
        #pragma unroll
        for (int c = 0; c < 64; c++) acc[c] = fmaf(cur.z, Wk[128 + c], acc[c]);
        #pragma unroll
        for (int c = 0; c < 64; c++) acc[c] = fmaf(cur.w, Wk[192 + c], acc[c]);
    }
    const float4* tr = (const float4*)(topo + (size_t)n * 8);
    float4 t0 = tr[0], t1 = tr[1];
    float tv[8] = {t0.x, t0.y, t0.z, t0.w, t1.x, t1.y, t1.z, t1.w};
    #pragma unroll
    for (int j = 0; j < 8; j++) {
        const float* Wk = W1 + (128 + j) * 64;
        #pragma unroll
        for (int c = 0; c < 64; c++) acc[c] = fmaf(tv[j], Wk[c], acc[c]);
    }
    float4* ho = (float4*)(h1 + (size_t)n * 64);
    #pragma unroll
    for (int q = 0; q < 16; q++)
        ho[q] = make_float4(acc[4 * q], acc[4 * q + 1], acc[4 * q + 2], acc[4 * q + 3]);
    float svv[8], dvv[8];
    #pragma unroll
    for (int h = 0; h < 8; h++) {
        float s = 0.f, d = 0.f;
        #pragma unroll
        for (int ch = 0; ch < 8; ch++) {
            s = fmaf(acc[h * 8 + ch], asrc[h * 8 + ch], s);
            d = fmaf(acc[h * 8 + ch], adst[h * 8 + ch], d);
        }
        svv[h] = s; dvv[h] = d;
    }
    float4* aso = (float4*)(as1 + (size_t)n * 8);
    aso[0] = make_float4(svv[0], svv[1], svv[2], svv[3]);
    aso[1] = make_float4(svv[4], svv[5], svv[6], svv[7]);
    float4* ado = (float4*)(ad1 + (size_t)n * 8);
    ado[0] = make_float4(dvv[0], dvv[1], dvv[2], dvv[3]);
    ado[1] = make_float4(dvv[4], dvv[5], dvv[6], dvv[7]);
}

// Per-dst softmax-weighted aggregation over in-edges (+ implicit self loop).
// Edge loop unrolled x8: 8 outstanding 256B row gathers per wave.
__global__ __launch_bounds__(256) void k_agg1(const float* __restrict__ h1,
                                              const float* __restrict__ as1,
                                              const float* __restrict__ ad1,
                                              const float* __restrict__ b1,
                                              const int* __restrict__ rowptr,
                                              const int* __restrict__ csr,
                                              float* __restrict__ h2, int N) {
    int tid = threadIdx.x, lane = tid & 63;
    int n = blockIdx.x * 4 + (tid >> 6);
    if (n >= N) return;
    int myh = lane >> 3;
    float ad_d = ad1[n * 8 + myh];
    float e0 = as1[n * 8 + myh] + ad_d;  // self loop
    float w0s = __expf(e0 >= 0.f ? e0 : 0.2f * e0);
    float acc0 = w0s * h1[(size_t)n * 64 + lane], z0 = w0s;
    float acc1 = 0.f, z1 = 0.f, acc2 = 0.f, z2 = 0.f, acc3 = 0.f, z3 = 0.f;
    int j0 = rowptr[n], j1 = rowptr[n + 1];
    int j = j0;
    for (; j + 8 <= j1; j += 8) {
        int s0 = csr[j + 0], s1 = csr[j + 1], s2 = csr[j + 2], s3 = csr[j + 3];
        int s4 = csr[j + 4], s5 = csr[j + 5], s6 = csr[j + 6], s7 = csr[j + 7];
        float f0 = h1[(size_t)s0 * 64 + lane];
        float f1 = h1[(size_t)s1 * 64 + lane];
        float f2 = h1[(size_t)s2 * 64 + lane];
        float f3 = h1[(size_t)s3 * 64 + lane];
        float f4 = h1[(size_t)s4 * 64 + lane];
        float f5 = h1[(size_t)s5 * 64 + lane];
        float f6 = h1[(size_t)s6 * 64 + lane];
        float f7 = h1[(size_t)s7 * 64 + lane];
        float a0 = as1[s0 * 8 + myh], a1 = as1[s1 * 8 + myh];
        float a2 = as1[s2 * 8 + myh], a3 = as1[s3 * 8 + myh];
        float a4 = as1[s4 * 8 + myh], a5 = as1[s5 * 8 + myh];
        float a6 = as1[s6 * 8 + myh], a7 = as1[s7 * 8 + myh];
        float q0 = a0 + ad_d, q1 = a1 + ad_d, q2 = a2 + ad_d, q3 = a3 + ad_d;
        float q4 = a4 + ad_d, q5 = a5 + ad_d, q6 = a6 + ad_d, q7 = a7 + ad_d;
        float w0 = __expf(q0 >= 0.f ? q0 : 0.2f * q0);
        float w1 = __expf(q1 >= 0.f ? q1 : 0.2f * q1);
        float w2 = __expf(q2 >= 0.f ? q2 : 0.2f * q2);
        float w3 = __expf(q3 >= 0.f ? q3 : 0.2f * q3);
        float w4 = __expf(q4 >= 0.f ? q4 : 0.2f * q4);
        float w5 = __expf(q5 >= 0.f ? q5 : 0.2f * q5);
        float w6 = __expf(q6 >= 0.f ? q6 : 0.2f * q6);
        float w7 = __expf(q7 >= 0.f ? q7 : 0.2f * q7);
        acc0 = fmaf(w0, f0, acc0); z0 += w0;
        acc1 = fmaf(w1, f1, acc1); z1 += w1;
        acc2 = fmaf(w2, f2, acc2); z2 += w2;
        acc3 = fmaf(w3, f3, acc3); z3 += w3;
        acc0 = fmaf(w4, f4, acc0); z0 += w4;
        acc1 = fmaf(w5, f5, acc1); z1 += w5;
        acc2 = fmaf(w6, f6, acc2); z2 += w6;
        acc3 = fmaf(w7, f7, acc3); z3 += w7;
    }
    for (; j < j1; ++j) {
        int s = csr[j];
        float e = as1[s * 8 + myh] + ad_d;
        float ww = __expf(e >= 0.f ? e : 0.2f * e);
        acc0 = fmaf(ww, h1[(size_t)s * 64 + lane], acc0);
        z0 += ww;
    }
    float acc = (acc0 + acc1) + (acc2 + acc3);
    float z = (z0 + z1) + (z2 + z3);
    float v = acc / (z + 1e-16f) + b1[lane];
    h2[(size_t)n * 64 + lane] = v > 0.f ? v : (__expf(v) - 1.f);  // ELU
}

// g[n][40] = h2[n] @ W2 ; scalar attention dots as2[n], ad2[n].
// Thread = node; same structure as k_xform1.
__global__ __launch_bounds__(256, 4) void k_xform2(const float* __restrict__ h2,
                                                   const float* __restrict__ W2,
                                                   const float* __restrict__ asrc2,
                                                   const float* __restrict__ adst2,
                                                   float* __restrict__ g,
                                                   float* __restrict__ as2,
                                                   float* __restrict__ ad2, int N) {
    int n = blockIdx.x * 256 + threadIdx.x;
    if (n >= N) n = N - 1;
    const float4* hr = (const float4*)(h2 + (size_t)n * 64);
    float acc[40];
    #pragma unroll
    for (int c = 0; c < 40; c++) acc[c] = 0.f;
    float4 xv = hr[0];
    #pragma unroll 1
    for (int k4 = 0; k4 < 16; k4++) {
        float4 cur = xv;
        if (k4 < 15) xv = hr[k4 + 1];
        const float* Wk = W2 + k4 * 160;  // rows 4k..4k+3 of W2[64][40]
        #pragma unroll
        for (int c = 0; c < 40; c++) acc[c] = fmaf(cur.x, Wk[c], acc[c]);
        #pragma unroll
        for (int c = 0; c < 40; c++) acc[c] = fmaf(cur.y, Wk[40 + c], acc[c]);
        #pragma unroll
        for (int c = 0; c < 40; c++) acc[c] = fmaf(cur.z, Wk[80 + c], acc[c]);
        #pragma unroll
        for (int c = 0; c < 40; c++) acc[c] = fmaf(cur.w, Wk[120 + c], acc[c]);
    }
    float s = 0.f, d = 0.f;
    #pragma unroll
    for (int c = 0; c < 40; c++) {
        s = fmaf(acc[c], asrc2[c], s);
        d = fmaf(acc[c], adst2[c], d);
    }
    as2[n] = s;
    ad2[n] = d;
    float4* go = (float4*)(g + (size_t)n * 40);
    #pragma unroll
    for (int q = 0; q < 10; q++)
        go[q] = make_float4(acc[4 * q], acc[4 * q + 1], acc[4 * q + 2], acc[4 * q + 3]);
}

// Layer-2 aggregation + bias + log_softmax. Edge loop unrolled x8.
__global__ __launch_bounds__(256) void k_agg2(const float* __restrict__ g,
                                              const float* __restrict__ as2,
                                              const float* __restrict__ ad2,
                                              const float* __restrict__ b2,
                                              const int* __restrict__ rowptr,
                                              const int* __restrict__ csr,
                                              float* __restrict__ out, int N) {
    int tid = threadIdx.x, lane = tid & 63;
    int n = blockIdx.x * 4 + (tid >> 6);
    if (n >= N) return;
    int c = (lane < 40) ? lane : 0;
    float add = ad2[n];
    float e0 = as2[n] + add;
    float w0s = __expf(e0 >= 0.f ? e0 : 0.2f * e0);
    float acc0 = w0s * g[(size_t)n * 40 + c], z0 = w0s;
    float acc1 = 0.f, z1 = 0.f, acc2 = 0.f, z2 = 0.f, acc3 = 0.f, z3 = 0.f;
    int j0 = rowptr[n], j1 = rowptr[n + 1];
    int j = j0;
    for (; j + 8 <= j1; j += 8) {
        int s0 = csr[j + 0], s1 = csr[j + 1], s2 = csr[j + 2], s3 = csr[j + 3];
        int s4 = csr[j + 4], s5 = csr[j + 5], s6 = csr[j + 6], s7 = csr[j + 7];
        float f0 = g[(size_t)s0 * 40 + c];
        float f1 = g[(size_t)s1 * 40 + c];
        float f2 = g[(size_t)s2 * 40 + c];
        float f3 = g[(size_t)s3 * 40 + c];
        float f4 = g[(size_t)s4 * 40 + c];
        float f5 = g[(size_t)s5 * 40 + c];
        float f6 = g[(size_t)s6 * 40 + c];
        float f7 = g[(size_t)s7 * 40 + c];
        float a0 = as2[s0], a1 = as2[s1], a2 = as2[s2], a3 = as2[s3];
        float a4 = as2[s4], a5 = as2[s5], a6 = as2[s6], a7 = as2[s7];
        float q0 = a0 + add, q1 = a1 + add, q2 = a2 + add, q3 = a3 + add;
        float q4 = a4 + add, q5 = a5 + add, q6 = a6 + add, q7 = a7 + add;
        float w0 = __expf(q0 >= 0.f ? q0 : 0.2f * q0);
        float w1 = __expf(q1 >= 0.f ? q1 : 0.2f * q1);
        float w2 = __expf(q2 >= 0.f ? q2 : 0.2f * q2);
        float w3 = __expf(q3 >= 0.f ? q3 : 0.2f * q3);
        float w4 = __expf(q4 >= 0.f ? q4 : 0.2f * q4);
        float w5 = __expf(q5 >= 0.f ? q5 : 0.2f * q5);
        float w6 = __expf(q6 >= 0.f ? q6 : 0.2f * q6);
        float w7 = __expf(q7 >= 0.f ? q7 : 0.2f * q7);
        acc0 = fmaf(w0, f0, acc0); z0 += w0;
        acc1 = fmaf(w1, f1, acc1); z1 += w1;
        acc2 = fmaf(w2, f2, acc2); z2 += w2;
        acc3 = fmaf(w3, f3, acc3); z3 += w3;
        acc0 = fmaf(w4, f4, acc0); z0 += w4;
        acc1 = fmaf(w5, f5, acc1); z1 += w5;
        acc2 = fmaf(w6, f6, acc2); z2 += w6;
        acc3 = fmaf(w7, f7, acc3); z3 += w7;
    }
    for (; j < j1; ++j) {
        int s = csr[j];
        float e = as2[s] + add;
        float ww = __expf(e >= 0.f ? e : 0.2f * e);
        acc0 = fmaf(ww, g[(size_t)s * 40 + c], acc0);
        z0 += ww;
    }
    float acc = (acc0 + acc1) + (acc2 + acc3);
    float z = (z0 + z1) + (z2 + z3);
    float logit = acc / (z + 1e-16f) + b2[c];
    float mv = (lane < 40) ? logit : -INFINITY;
    #pragma unroll
    for (int ofs = 1; ofs < 64; ofs <<= 1) mv = fmaxf(mv, __shfl_xor(mv, ofs));
    float ev = (lane < 40) ? __expf(logit - mv) : 0.f;
    #pragma unroll
    for (int ofs = 1; ofs < 64; ofs <<= 1) ev += __shfl_xor(ev, ofs);
    if (lane < 40) out[n * 40 + lane] = logit - mv - __logf(ev);
}

extern "C" void kernel_launch(void* const* d_in, const int* in_sizes, int n_in,
                              void* d_out, int out_size, void* d_ws, size_t ws_size,
                              hipStream_t stream) {
    const float* x    = (const float*)d_in[0];
    const float* topo = (const float*)d_in[1];
    const int*   ei   = (const int*)d_in[2];
    const float* W1   = (const float*)d_in[3];
    const float* a_s1 = (const float*)d_in[4];
    const float* a_d1 = (const float*)d_in[5];
    const float* b1   = (const float*)d_in[6];
    const float* W2   = (const float*)d_in[7];
    const float* a_s2 = (const float*)d_in[8];
    const float* a_d2 = (const float*)d_in[9];
    const float* b2   = (const float*)d_in[10];
    float* out = (float*)d_out;

    int N = in_sizes[0] / 128;
    int E = in_sizes[2] / 2;
    const int* esrc = ei;
    const int* edst = ei + E;
    int NBUK = (N + 255) / 256;

    char* ws = (char*)d_ws;
    size_t off = 0;
    auto alloc = [&](size_t bytes) -> void* {
        void* p = ws + off;
        off = (off + bytes + 255) & ~(size_t)255;
        return p;
    };
    float* h1     = (float*)alloc((size_t)N * 64 * 4);
    float* as1    = (float*)alloc((size_t)N * 8 * 4);
    float* ad1    = (float*)alloc((size_t)N * 8 * 4);
    float* h2     = (float*)alloc((size_t)N * 64 * 4);
    float* gbuf   = (float*)alloc((size_t)N * 40 * 4);
    float* as2    = (float*)alloc((size_t)N * 4);
    float* ad2    = (float*)alloc((size_t)N * 4);
    int*   rowptr = (int*)alloc((size_t)(N + 1) * 4);
    int*   csr    = (int*)alloc((size_t)E * 4);
    unsigned int* tmp = (unsigned int*)alloc((size_t)E * 4);
    int* bucketCnt = (int*)alloc((size_t)(NBUK + 1) * 4);
    int* bucketOff = (int*)alloc((size_t)(NBUK + 1) * 4);
    int* gCursor   = (int*)alloc((size_t)NBUK * 4);

    hipMemsetAsync(bucketCnt, 0, (size_t)(NBUK + 1) * 4, stream);
    k_bhist<<<256, 256, 0, stream>>>(edst, bucketCnt, E, NBUK);
    k_bscan<<<1, 64, 0, stream>>>(bucketCnt, bucketOff, gCursor, rowptr, N, E, NBUK);
    int nbin = (E + BIN_CHUNK - 1) / BIN_CHUNK;
    k_bin<<<nbin, 256, 0, stream>>>(esrc, edst, gCursor, tmp, E, NBUK);
    k_fill2<<<NBUK, 256, 0, stream>>>(tmp, bucketOff, rowptr, csr, N);

    int nbx = (N + 255) / 256;  // thread = node
    int nb4 = (N + 3) / 4;      // 1 node/wave x 4 waves/block
    k_xform1<<<nbx, 256, 0, stream>>>(x, topo, W1, a_s1, a_d1, h1, as1, ad1, N);
    k_agg1<<<nb4, 256, 0, stream>>>(h1, as1, ad1, b1, rowptr, csr, h2, N);
    k_xform2<<<nbx, 256, 0, stream>>>(h2, W2, a_s2, a_d2, gbuf, as2, ad2, N);
    k_agg2<<<nb4, 256, 0, stream>>>(gbuf, as2, ad2, b2, rowptr, csr, out, N);
}